// Round 1
// baseline (395.807 us; speedup 1.0000x reference)
//
#include <hip/hip_runtime.h>
#include <math.h>

using bfrag8 = __attribute__((ext_vector_type(8))) short;
using facc4  = __attribute__((ext_vector_type(4))) float;

#define MFMA16(a,b,c) __builtin_amdgcn_mfma_f32_16x16x32_bf16((a),(b),(c),0,0,0)

#define T_SEQ 827
#define T_PAD 832
#define NHEAD 16

static __device__ __forceinline__ unsigned short f2bf(float f) {
    unsigned int x = __float_as_uint(f);
    unsigned int r = x + 0x7FFFu + ((x >> 16) & 1u);
    return (unsigned short)(r >> 16);
}

// ---------------- init min/max (per map: [2m]=min init +inf, [2m+1]=max init 0) ---
__global__ void k_init(float* minmax) {
    int i = threadIdx.x;
    if (i < 3) {
        ((unsigned int*)minmax)[2 * i]     = 0x7F800000u; // +inf
        ((unsigned int*)minmax)[2 * i + 1] = 0u;          // 0 (values >= 0)
    }
}

// ---------------- f32 -> bf16 convert (x), exact multiple of 1024 per block -------
__global__ __launch_bounds__(256) void k_convert(const float* __restrict__ in,
                                                 unsigned short* __restrict__ out) {
    int i = (blockIdx.x * 256 + threadIdx.x) * 4;
    float4 v = *reinterpret_cast<const float4*>(in + i);
    ushort4 o;
    o.x = f2bf(v.x); o.y = f2bf(v.y); o.z = f2bf(v.z); o.w = f2bf(v.w);
    *reinterpret_cast<ushort4*>(out + i) = o;
}

// ---------------- W (K x N) -> Wt bf16 (N x K) ------------------------------------
__global__ __launch_bounds__(256) void k_transpose(const float* __restrict__ W,
                                                   unsigned short* __restrict__ Wt) {
    __shared__ float tile[32][33];
    int bx = blockIdx.x, by = blockIdx.y;
    int tx = threadIdx.x & 31, ty0 = threadIdx.x >> 5; // 8 rows per pass
#pragma unroll
    for (int i = 0; i < 4; ++i) {
        int ty = ty0 + i * 8;
        tile[ty][tx] = W[(size_t)(by * 32 + ty) * 1024 + bx * 32 + tx];
    }
    __syncthreads();
#pragma unroll
    for (int i = 0; i < 4; ++i) {
        int ty = ty0 + i * 8;
        Wt[(size_t)(bx * 32 + ty) * 1024 + by * 32 + tx] = f2bf(tile[tx][ty]);
    }
}

// ---------------- blur: one block per (map, b, row-image) -------------------------
__global__ __launch_bounds__(256) void k_blur(const float* f01, const float* f02, const float* f12,
                                              const float* b01, const float* b02, const float* b12,
                                              float* __restrict__ bl, float* minmax) {
    int m = blockIdx.x >> 10, rem = blockIdx.x & 1023, b = rem >> 8, r = rem & 255;
    const float* f  = (m == 0) ? f01 : (m == 1) ? f02 : f12;
    const float* bm = (m == 0) ? b01 : (m == 1) ? b02 : b12;
    int tid = threadIdx.x, i = tid >> 4, j = tid & 15;

    float k1[7]; float ks = 0.f;
#pragma unroll
    for (int d = 0; d < 7; ++d) { float hx = (float)d - 3.f; k1[d] = expf(-0.5f * hx * hx / 2.25f); ks += k1[d]; }
#pragma unroll
    for (int d = 0; d < 7; ++d) k1[d] /= ks;

    __shared__ float img[16][17], tmp[16][17];
    size_t idx = (size_t)b * 65536 + (size_t)r * 256 + tid;
    float bi = f[idx] * bm[(size_t)b * 65536 + (size_t)tid * 256 + r]; // b_perm[r][c] = b[c][r]
    img[i][j] = bi;
    __syncthreads();
    float ha = 0.f;
#pragma unroll
    for (int d = 0; d < 7; ++d) { int p = j - 3 + d; p = p < 0 ? -p : (p > 15 ? 30 - p : p); ha += k1[d] * img[i][p]; }
    tmp[i][j] = ha;
    __syncthreads();
    float v = 0.f;
#pragma unroll
    for (int d = 0; d < 7; ++d) { int p = i - 3 + d; p = p < 0 ? -p : (p > 15 ? 30 - p : p); v += k1[d] * tmp[p][j]; }
    bl[(size_t)m * 262144 + idx] = v;

    // block reduce min/max, then atomics (values >= 0 -> int ordering exact)
    float mn = v, mx = v;
#pragma unroll
    for (int off = 32; off; off >>= 1) { mn = fminf(mn, __shfl_xor(mn, off)); mx = fmaxf(mx, __shfl_xor(mx, off)); }
    __shared__ float smn[4], smx[4];
    int wid = tid >> 6, lane = tid & 63;
    if (lane == 0) { smn[wid] = mn; smx[wid] = mx; }
    __syncthreads();
    if (tid == 0) {
        mn = fminf(fminf(smn[0], smn[1]), fminf(smn[2], smn[3]));
        mx = fmaxf(fmaxf(smx[0], smx[1]), fmaxf(smx[2], smx[3]));
        atomicMin((int*)minmax + 2 * m,     __float_as_int(mn));
        atomicMax((int*)minmax + 2 * m + 1, __float_as_int(mx));
    }
}

// ---------------- finalize masks = clip01((bl-mn)/(mx-mn)) * f * b^T --------------
__global__ __launch_bounds__(256) void k_finalize(const float* f01, const float* f02, const float* f12,
                                                  const float* b01, const float* b02, const float* b12,
                                                  const float* __restrict__ bl, const float* minmax,
                                                  float* __restrict__ masks) {
    int m = blockIdx.x >> 10, rem = blockIdx.x & 1023, b = rem >> 8, r = rem & 255;
    const float* f  = (m == 0) ? f01 : (m == 1) ? f02 : f12;
    const float* bm = (m == 0) ? b01 : (m == 1) ? b02 : b12;
    int tid = threadIdx.x;
    size_t idx = (size_t)b * 65536 + (size_t)r * 256 + tid;
    float mn = minmax[2 * m], mx = minmax[2 * m + 1];
    float w = (bl[(size_t)m * 262144 + idx] - mn) / (mx - mn);
    w = fminf(fmaxf(w, 0.f), 1.f);
    masks[(size_t)m * 262144 + idx] = w * f[idx] * bm[(size_t)b * 65536 + (size_t)tid * 256 + r];
}

// ---------------- GEMM: C[M x 1024] = A[M x 1024](bf16) * Wt^T + bias -------------
// MODE 0: out bf16 (B,NH,T_PAD,64) ; MODE 1: out bf16 (B,NH,64,T_PAD) [V^T] ;
// MODE 2: out f32 row-major (M x 1024)
template<int MODE>
__global__ __launch_bounds__(256) void k_gemm(const unsigned short* __restrict__ A,
                                              const unsigned short* __restrict__ Bt,
                                              const float* __restrict__ bias,
                                              void* __restrict__ outv, int M) {
    __shared__ unsigned short As[64][40];
    __shared__ unsigned short Bs[64][40];
    int m0 = blockIdx.x * 64, n0 = blockIdx.y * 64;
    int tid = threadIdx.x;
    int wid = tid >> 6, lane = tid & 63;
    int g = lane >> 4, l15 = lane & 15;
    int wm = wid >> 1, wn = wid & 1;
    facc4 acc[2][2] = {};
    int lr = tid >> 2;          // staging row 0..63
    int lk = (tid & 3) * 8;     // staging k offset
    int arow = m0 + lr;
    uint4 zero4 = {0, 0, 0, 0};

    for (int k0 = 0; k0 < 1024; k0 += 32) {
        if (k0) __syncthreads();
        uint4 av = (arow < M) ? *reinterpret_cast<const uint4*>(A + (size_t)arow * 1024 + k0 + lk) : zero4;
        uint4 bv = *reinterpret_cast<const uint4*>(Bt + (size_t)(n0 + lr) * 1024 + k0 + lk);
        *reinterpret_cast<uint4*>(&As[lr][lk]) = av;
        *reinterpret_cast<uint4*>(&Bs[lr][lk]) = bv;
        __syncthreads();
        bfrag8 af[2], bfr[2];
#pragma unroll
        for (int mi = 0; mi < 2; ++mi)
            af[mi] = *reinterpret_cast<const bfrag8*>(&As[wm * 32 + mi * 16 + l15][g * 8]);
#pragma unroll
        for (int ni = 0; ni < 2; ++ni)
            bfr[ni] = *reinterpret_cast<const bfrag8*>(&Bs[wn * 32 + ni * 16 + l15][g * 8]);
#pragma unroll
        for (int mi = 0; mi < 2; ++mi)
#pragma unroll
            for (int ni = 0; ni < 2; ++ni)
                acc[mi][ni] = MFMA16(af[mi], bfr[ni], acc[mi][ni]);
    }

#pragma unroll
    for (int mi = 0; mi < 2; ++mi)
#pragma unroll
        for (int ni = 0; ni < 2; ++ni)
#pragma unroll
            for (int r = 0; r < 4; ++r) {
                int row = m0 + wm * 32 + mi * 16 + g * 4 + r;
                int col = n0 + wn * 32 + ni * 16 + l15;
                if (row >= M) continue;
                float v = acc[mi][ni][r] + bias[col];
                if (MODE == 2) {
                    reinterpret_cast<float*>(outv)[(size_t)row * 1024 + col] = v;
                } else {
                    int b = row / T_SEQ, t = row % T_SEQ;
                    int hh = col >> 6, d = col & 63;
                    unsigned short* o = reinterpret_cast<unsigned short*>(outv);
                    if (MODE == 0) o[(((size_t)(b * NHEAD + hh)) * T_PAD + t) * 64 + d] = f2bf(v);
                    else           o[(((size_t)(b * NHEAD + hh)) * 64 + d) * T_PAD + t] = f2bf(v);
                }
            }
}

// ---------------- zero the T_PAD tails of q/k/vT ----------------------------------
__global__ __launch_bounds__(256) void k_zero(unsigned short* q, unsigned short* k, unsigned short* vT) {
    int bh = blockIdx.x, tid = threadIdx.x;
    for (int i = tid; i < 320; i += 256) {
        int t = 827 + i / 64, d = i % 64;
        q[((size_t)bh * T_PAD + t) * 64 + d] = 0;
        k[((size_t)bh * T_PAD + t) * 64 + d] = 0;
        int dd = i / 5, s = 827 + (i % 5);
        vT[((size_t)bh * 64 + dd) * T_PAD + s] = 0;
    }
}

// ---------------- flash attention: 4 waves/block, 16 q-rows/wave, s-tile 32 -------
__global__ __launch_bounds__(256) void k_attn(const unsigned short* __restrict__ qb,
                                              const unsigned short* __restrict__ kb,
                                              const unsigned short* __restrict__ vT,
                                              const float* __restrict__ h,
                                              const float* __restrict__ masks,
                                              unsigned short* __restrict__ y) {
    int blk = blockIdx.x;
    int bh = blk / 13, qt = blk % 13;
    int b = bh >> 4, hh = bh & 15;
    int tid = threadIdx.x, wid = tid >> 6, lane = tid & 63;
    int g = lane >> 4, l15 = lane & 15;
    int t0 = qt * 64 + wid * 16;

    __shared__ unsigned short plds[4][16 * 40]; // per-wave P tile, stride 40 bf16
    unsigned short* pw = &plds[wid][0];

    size_t qrow = ((size_t)bh * T_PAD + t0 + l15) * 64 + g * 8;
    bfrag8 aq0 = *reinterpret_cast<const bfrag8*>(qb + qrow);
    bfrag8 aq1 = *reinterpret_cast<const bfrag8*>(qb + qrow + 32);

    float m_r[4], l_r[4];
    facc4 acc[4] = {};
#pragma unroll
    for (int r = 0; r < 4; ++r) { m_r[r] = -__builtin_inff(); l_r[r] = 0.f; }

    int tmax = t0 + 15; if (tmax > 826) tmax = 826;
    const float* hb = h + (size_t)bh * 827 * 827;

    for (int s0 = 0; s0 <= tmax; s0 += 32) {
        facc4 sf[2] = {};
#pragma unroll
        for (int nt = 0; nt < 2; ++nt) {
            size_t krow = ((size_t)bh * T_PAD + s0 + nt * 16 + l15) * 64 + g * 8;
            bfrag8 k0f = *reinterpret_cast<const bfrag8*>(kb + krow);
            bfrag8 k1f = *reinterpret_cast<const bfrag8*>(kb + krow + 32);
            sf[nt] = MFMA16(aq0, k0f, sf[nt]);
            sf[nt] = MFMA16(aq1, k1f, sf[nt]);
        }
        float rmax[4] = { -__builtin_inff(), -__builtin_inff(), -__builtin_inff(), -__builtin_inff() };
#pragma unroll
        for (int nt = 0; nt < 2; ++nt)
#pragma unroll
            for (int r = 0; r < 4; ++r) {
                int t = t0 + g * 4 + r;
                int s = s0 + nt * 16 + l15;
                float sc = -__builtin_inff();
                if (t < 827 && s <= t) {
                    sc = sf[nt][r] * 0.125f + hb[(size_t)t * 827 + s];
                    if (s < 256) {
                        if (t >= 285 && t < 541)
                            sc *= masks[(size_t)b * 65536 + (size_t)(t - 285) * 256 + s];
                        else if (t >= 571)
                            sc *= masks[262144 + (size_t)b * 65536 + (size_t)(t - 571) * 256 + s];
                    } else if (s >= 286 && s < 542 && t >= 571) {
                        sc *= masks[524288 + (size_t)b * 65536 + (size_t)(t - 571) * 256 + (s - 286)];
                    }
                }
                sf[nt][r] = sc;
                rmax[r] = fmaxf(rmax[r], sc);
            }
#pragma unroll
        for (int r = 0; r < 4; ++r) {
#pragma unroll
            for (int off = 8; off; off >>= 1) rmax[r] = fmaxf(rmax[r], __shfl_xor(rmax[r], off));
        }
#pragma unroll
        for (int r = 0; r < 4; ++r) {
            float mn = fmaxf(m_r[r], rmax[r]);
            float scale = __expf(m_r[r] - mn);
            float p0 = __expf(sf[0][r] - mn);
            float p1 = __expf(sf[1][r] - mn);
            sf[0][r] = p0; sf[1][r] = p1;
            float ps = p0 + p1;
#pragma unroll
            for (int off = 8; off; off >>= 1) ps += __shfl_xor(ps, off);
            l_r[r] = l_r[r] * scale + ps;
            m_r[r] = mn;
#pragma unroll
            for (int dt = 0; dt < 4; ++dt) acc[dt][r] *= scale;
        }
        // P -> LDS (bf16), then read back as A-fragment
#pragma unroll
        for (int nt = 0; nt < 2; ++nt)
#pragma unroll
            for (int r = 0; r < 4; ++r)
                pw[(g * 4 + r) * 40 + nt * 16 + l15] = f2bf(sf[nt][r]);
        bfrag8 ap = *reinterpret_cast<const bfrag8*>(&pw[l15 * 40 + g * 8]);
#pragma unroll
        for (int dt = 0; dt < 4; ++dt) {
            bfrag8 bv = *reinterpret_cast<const bfrag8*>(vT + ((size_t)bh * 64 + dt * 16 + l15) * T_PAD + s0 + g * 8);
            acc[dt] = MFMA16(ap, bv, acc[dt]);
        }
    }
#pragma unroll
    for (int dt = 0; dt < 4; ++dt)
#pragma unroll
        for (int r = 0; r < 4; ++r) {
            int t = t0 + g * 4 + r;
            if (t < 827)
                y[((size_t)(b * 827) + t) * 1024 + hh * 64 + dt * 16 + l15] = f2bf(acc[dt][r] / l_r[r]);
        }
}

extern "C" void kernel_launch(void* const* d_in, const int* in_sizes, int n_in,
                              void* d_out, int out_size, void* d_ws, size_t ws_size,
                              hipStream_t stream) {
    const float* x   = (const float*)d_in[0];
    const float* h   = (const float*)d_in[1];
    const float* f01 = (const float*)d_in[2];
    const float* f02 = (const float*)d_in[3];
    const float* f12 = (const float*)d_in[4];
    const float* b01 = (const float*)d_in[5];
    const float* b02 = (const float*)d_in[6];
    const float* b12 = (const float*)d_in[7];
    const float* Wq  = (const float*)d_in[8];
    const float* bq  = (const float*)d_in[9];
    const float* Wk  = (const float*)d_in[10];
    const float* bk  = (const float*)d_in[11];
    const float* Wv  = (const float*)d_in[12];
    const float* bv  = (const float*)d_in[13];
    const float* Wp  = (const float*)d_in[14];
    const float* bp  = (const float*)d_in[15];

    char* ws = (char*)d_ws;
    float* minmax = (float*)ws;
    float* bl     = (float*)(ws + 256);
    float* masks  = (float*)(ws + 256 + 3145728);
    unsigned short* x_bf = (unsigned short*)(ws + 256 + 2 * 3145728);
    unsigned short* WtQ  = x_bf + (size_t)3308 * 1024;
    unsigned short* WtK  = WtQ + 1048576;
    unsigned short* WtV  = WtK + 1048576;
    unsigned short* WtP  = WtV + 1048576;
    unsigned short* q_bf = WtP + 1048576;
    unsigned short* k_bf = q_bf + (size_t)64 * T_PAD * 64;
    unsigned short* vTb  = k_bf + (size_t)64 * T_PAD * 64;
    unsigned short* y_bf = vTb  + (size_t)64 * T_PAD * 64;

    k_init<<<1, 64, 0, stream>>>(minmax);
    k_convert<<<3308, 256, 0, stream>>>(x, x_bf);
    dim3 tg(32, 32);
    k_transpose<<<tg, 256, 0, stream>>>(Wq, WtQ);
    k_transpose<<<tg, 256, 0, stream>>>(Wk, WtK);
    k_transpose<<<tg, 256, 0, stream>>>(Wv, WtV);
    k_transpose<<<tg, 256, 0, stream>>>(Wp, WtP);
    k_blur<<<3072, 256, 0, stream>>>(f01, f02, f12, b01, b02, b12, bl, minmax);
    k_finalize<<<3072, 256, 0, stream>>>(f01, f02, f12, b01, b02, b12, bl, minmax, masks);
    dim3 gg(52, 16);
    k_gemm<0><<<gg, 256, 0, stream>>>(x_bf, WtQ, bq, q_bf, 3308);
    k_gemm<0><<<gg, 256, 0, stream>>>(x_bf, WtK, bk, k_bf, 3308);
    k_gemm<1><<<gg, 256, 0, stream>>>(x_bf, WtV, bv, vTb, 3308);
    k_zero<<<64, 256, 0, stream>>>(q_bf, k_bf, vTb);
    k_attn<<<832, 256, 0, stream>>>(q_bf, k_bf, vTb, h, masks, y_bf);
    k_gemm<2><<<gg, 256, 0, stream>>>(y_bf, WtP, bp, d_out, 3308);
}

// Round 2
// 243.012 us; speedup vs baseline: 1.6288x; 1.6288x over previous
//
#include <hip/hip_runtime.h>
#include <math.h>

using bfrag8 = __attribute__((ext_vector_type(8))) short;
using facc4  = __attribute__((ext_vector_type(4))) float;

#define MFMA16(a,b,c) __builtin_amdgcn_mfma_f32_16x16x32_bf16((a),(b),(c),0,0,0)

#define T_SEQ 827
#define T_PAD 832
#define NHEAD 16
#define NEG_INF (-__builtin_inff())

static __device__ __forceinline__ unsigned short f2bf(float f) {
    unsigned int x = __float_as_uint(f);
    unsigned int r = x + 0x7FFFu + ((x >> 16) & 1u);
    return (unsigned short)(r >> 16);
}

// global -> LDS async copy, 16B per lane. LDS dest must be wave-uniform base (+lane*16 auto).
static __device__ __forceinline__ void gl16(const unsigned short* g, unsigned short* l) {
    __builtin_amdgcn_global_load_lds(
        (const __attribute__((address_space(1))) unsigned int*)g,
        (__attribute__((address_space(3))) unsigned int*)l,
        16, 0, 0);
}

// ---------------- init min/max ----------------------------------------------------
__global__ void k_init(float* minmax) {
    int i = threadIdx.x;
    if (i < 3) {
        ((unsigned int*)minmax)[2 * i]     = 0x7F800000u; // +inf
        ((unsigned int*)minmax)[2 * i + 1] = 0u;          // 0 (values >= 0)
    }
}

// ---------------- f32 -> bf16 convert (x) -----------------------------------------
__global__ __launch_bounds__(256) void k_convert(const float* __restrict__ in,
                                                 unsigned short* __restrict__ out) {
    int i = (blockIdx.x * 256 + threadIdx.x) * 4;
    float4 v = *reinterpret_cast<const float4*>(in + i);
    ushort4 o;
    o.x = f2bf(v.x); o.y = f2bf(v.y); o.z = f2bf(v.z); o.w = f2bf(v.w);
    *reinterpret_cast<ushort4*>(out + i) = o;
}

// ---------------- W (K x N) -> Wt bf16 (N x K) ------------------------------------
__global__ __launch_bounds__(256) void k_transpose(const float* __restrict__ W,
                                                   unsigned short* __restrict__ Wt) {
    __shared__ float tile[32][33];
    int bx = blockIdx.x, by = blockIdx.y;
    int tx = threadIdx.x & 31, ty0 = threadIdx.x >> 5;
#pragma unroll
    for (int i = 0; i < 4; ++i) {
        int ty = ty0 + i * 8;
        tile[ty][tx] = W[(size_t)(by * 32 + ty) * 1024 + bx * 32 + tx];
    }
    __syncthreads();
#pragma unroll
    for (int i = 0; i < 4; ++i) {
        int ty = ty0 + i * 8;
        Wt[(size_t)(bx * 32 + ty) * 1024 + by * 32 + tx] = f2bf(tile[tx][ty]);
    }
}

// ---------------- blur ------------------------------------------------------------
__global__ __launch_bounds__(256) void k_blur(const float* f01, const float* f02, const float* f12,
                                              const float* b01, const float* b02, const float* b12,
                                              float* __restrict__ bl, float* minmax) {
    int m = blockIdx.x >> 10, rem = blockIdx.x & 1023, b = rem >> 8, r = rem & 255;
    const float* f  = (m == 0) ? f01 : (m == 1) ? f02 : f12;
    const float* bm = (m == 0) ? b01 : (m == 1) ? b02 : b12;
    int tid = threadIdx.x, i = tid >> 4, j = tid & 15;

    float k1[7]; float ks = 0.f;
#pragma unroll
    for (int d = 0; d < 7; ++d) { float hx = (float)d - 3.f; k1[d] = expf(-0.5f * hx * hx / 2.25f); ks += k1[d]; }
#pragma unroll
    for (int d = 0; d < 7; ++d) k1[d] /= ks;

    __shared__ float img[16][17], tmp[16][17];
    size_t idx = (size_t)b * 65536 + (size_t)r * 256 + tid;
    float bi = f[idx] * bm[(size_t)b * 65536 + (size_t)tid * 256 + r];
    img[i][j] = bi;
    __syncthreads();
    float ha = 0.f;
#pragma unroll
    for (int d = 0; d < 7; ++d) { int p = j - 3 + d; p = p < 0 ? -p : (p > 15 ? 30 - p : p); ha += k1[d] * img[i][p]; }
    tmp[i][j] = ha;
    __syncthreads();
    float v = 0.f;
#pragma unroll
    for (int d = 0; d < 7; ++d) { int p = i - 3 + d; p = p < 0 ? -p : (p > 15 ? 30 - p : p); v += k1[d] * tmp[p][j]; }
    bl[(size_t)m * 262144 + idx] = v;

    float mn = v, mx = v;
#pragma unroll
    for (int off = 32; off; off >>= 1) { mn = fminf(mn, __shfl_xor(mn, off)); mx = fmaxf(mx, __shfl_xor(mx, off)); }
    __shared__ float smn[4], smx[4];
    int wid = tid >> 6, lane = tid & 63;
    if (lane == 0) { smn[wid] = mn; smx[wid] = mx; }
    __syncthreads();
    if (tid == 0) {
        mn = fminf(fminf(smn[0], smn[1]), fminf(smn[2], smn[3]));
        mx = fmaxf(fmaxf(smx[0], smx[1]), fmaxf(smx[2], smx[3]));
        atomicMin((int*)minmax + 2 * m,     __float_as_int(mn));
        atomicMax((int*)minmax + 2 * m + 1, __float_as_int(mx));
    }
}

// ---------------- finalize masks --------------------------------------------------
__global__ __launch_bounds__(256) void k_finalize(const float* f01, const float* f02, const float* f12,
                                                  const float* b01, const float* b02, const float* b12,
                                                  const float* __restrict__ bl, const float* minmax,
                                                  float* __restrict__ masks) {
    int m = blockIdx.x >> 10, rem = blockIdx.x & 1023, b = rem >> 8, r = rem & 255;
    const float* f  = (m == 0) ? f01 : (m == 1) ? f02 : f12;
    const float* bm = (m == 0) ? b01 : (m == 1) ? b02 : b12;
    int tid = threadIdx.x;
    size_t idx = (size_t)b * 65536 + (size_t)r * 256 + tid;
    float mn = minmax[2 * m], mx = minmax[2 * m + 1];
    float w = (bl[(size_t)m * 262144 + idx] - mn) / (mx - mn);
    w = fminf(fmaxf(w, 0.f), 1.f);
    masks[(size_t)m * 262144 + idx] = w * f[idx] * bm[(size_t)b * 65536 + (size_t)tid * 256 + r];
}

// ---------------- zero pads: q/k tail rows, vT full last s-chunk ------------------
__global__ __launch_bounds__(256) void k_zero(unsigned short* q, unsigned short* k, unsigned short* vT) {
    int bh = blockIdx.x, tid = threadIdx.x;
    for (int i = tid; i < 320; i += 256) {
        int t = 827 + i / 64, d = i % 64;
        q[((size_t)bh * T_PAD + t) * 64 + d] = 0;
        k[((size_t)bh * T_PAD + t) * 64 + d] = 0;
    }
    for (int i = tid; i < 4096; i += 256) {
        int d = i >> 6, s = 768 + (i & 63);
        vT[((size_t)bh * 64 + d) * T_PAD + s] = 0;
    }
}

// ---------------- GEMM 128x128 tile, BK=32, global_load_lds staging ---------------
// MODE 0: fused QKV (N=3072): which = n0>>10 -> q linear / k swizzled / vT swizzled
// MODE 2: f32 out (proj)
template<int MODE>
__global__ __launch_bounds__(256) void k_gemm(const unsigned short* __restrict__ A,
                                              const unsigned short* __restrict__ Bt,
                                              const float* __restrict__ b0, const float* __restrict__ b1,
                                              const float* __restrict__ b2,
                                              unsigned short* __restrict__ qo, unsigned short* __restrict__ ko,
                                              unsigned short* __restrict__ vo, float* __restrict__ fo, int M) {
    __shared__ unsigned short As[4096];
    __shared__ unsigned short Bs[4096];
    int m0 = blockIdx.x * 128, n0 = blockIdx.y * 128;
    int tid = threadIdx.x, wid = tid >> 6, lane = tid & 63;
    int g = lane >> 4, l15 = lane & 15;
    int wm = wid >> 1, wn = wid & 1;
    facc4 acc[4][4] = {};

    int ar0 = m0 + (tid >> 2); if (ar0 > M - 1) ar0 = M - 1;
    int ar1 = m0 + 64 + (tid >> 2); if (ar1 > M - 1) ar1 = M - 1;
    const unsigned short* Ap0 = A + (size_t)ar0 * 1024 + (tid & 3) * 8;
    const unsigned short* Ap1 = A + (size_t)ar1 * 1024 + (tid & 3) * 8;
    const unsigned short* Bp0 = Bt + (size_t)(n0 + (tid >> 2)) * 1024 + (tid & 3) * 8;
    const unsigned short* Bp1 = Bp0 + (size_t)64 * 1024;
    unsigned short* asw = As + (wid << 9);
    unsigned short* bsw = Bs + (wid << 9);

    for (int k0 = 0; k0 < 1024; k0 += 32) {
        if (k0) __syncthreads();
        gl16(Ap0 + k0, asw);
        gl16(Ap1 + k0, asw + 2048);
        gl16(Bp0 + k0, bsw);
        gl16(Bp1 + k0, bsw + 2048);
        __syncthreads();
        bfrag8 af[4], bf[4];
#pragma unroll
        for (int mi = 0; mi < 4; ++mi)
            af[mi] = *reinterpret_cast<const bfrag8*>(&As[(wm * 64 + mi * 16 + l15) * 32 + g * 8]);
#pragma unroll
        for (int ni = 0; ni < 4; ++ni)
            bf[ni] = *reinterpret_cast<const bfrag8*>(&Bs[(wn * 64 + ni * 16 + l15) * 32 + g * 8]);
#pragma unroll
        for (int mi = 0; mi < 4; ++mi)
#pragma unroll
            for (int ni = 0; ni < 4; ++ni)
                acc[mi][ni] = MFMA16(af[mi], bf[ni], acc[mi][ni]);
    }

    int which = n0 >> 10;
    const float* bb = (MODE == 2) ? b0 : (which == 0 ? b0 : (which == 1 ? b1 : b2));
#pragma unroll
    for (int mi = 0; mi < 4; ++mi)
#pragma unroll
        for (int ni = 0; ni < 4; ++ni)
#pragma unroll
            for (int r = 0; r < 4; ++r) {
                int row = m0 + wm * 64 + mi * 16 + g * 4 + r;
                if (row >= M) continue;
                int col = n0 + wn * 64 + ni * 16 + l15;
                float v = acc[mi][ni][r] + bb[col & 1023];
                if (MODE == 2) {
                    fo[(size_t)row * 1024 + col] = v;
                } else {
                    int b = row / T_SEQ, t = row - b * T_SEQ;
                    int cc = col & 1023;
                    int hh = cc >> 6, d = cc & 63;
                    size_t bh = (size_t)(b * NHEAD + hh);
                    if (which == 0) {
                        qo[(bh * T_PAD + t) * 64 + d] = f2bf(v);
                    } else if (which == 1) {
                        int du = (((d >> 3) ^ (t & 7)) << 3) | (d & 7);
                        ko[(bh * T_PAD + t) * 64 + du] = f2bf(v);
                    } else {
                        int sl = t & 63;
                        int su = (((sl >> 3) ^ (d & 7)) << 3) | (t & 7);
                        vo[(bh * 64 + d) * T_PAD + (t - sl) + su] = f2bf(v);
                    }
                }
            }
}

// ---------------- flash attention v2: s-tile 64, LDS K/V dbuf, h/mask prefetch ----
__global__ __launch_bounds__(256) void k_attn(const unsigned short* __restrict__ qb,
                                              const unsigned short* __restrict__ kb,
                                              const unsigned short* __restrict__ vT,
                                              const float* __restrict__ h,
                                              const float* __restrict__ maskp,
                                              unsigned short* __restrict__ y) {
    int blk = blockIdx.x;
    int bh = blk / 13;
    int qt = 12 - (blk % 13);       // long blocks first
    int b = bh >> 4, hh = bh & 15;
    int tid = threadIdx.x, wid = tid >> 6, lane = tid & 63;
    int g = lane >> 4, l15 = lane & 15;
    int t0 = qt * 64 + wid * 16;
    int ntiles = qt + 1;

    __shared__ unsigned short Ks[2][4096];
    __shared__ unsigned short Vs[2][4096];
    __shared__ unsigned short Ps[4][1024];
    unsigned short* pw = &Ps[wid][0];

    const unsigned short* Kbase = kb + (size_t)bh * T_PAD * 64;
    const unsigned short* Vbase = vT + (size_t)bh * 64 * T_PAD;
    const float* hb = h + (size_t)bh * T_SEQ * T_SEQ;

    // Q fragments (held in regs for whole kernel)
    size_t qrow = ((size_t)bh * T_PAD + t0 + l15) * 64 + g * 8;
    bfrag8 aq0 = *reinterpret_cast<const bfrag8*>(qb + qrow);
    bfrag8 aq1 = *reinterpret_cast<const bfrag8*>(qb + qrow + 32);

    float m_r[4], l_r[4];
    facc4 acc[4] = {};
#pragma unroll
    for (int r = 0; r < 4; ++r) { m_r[r] = NEG_INF; l_r[r] = 0.f; }

    // ---- helpers as lambdas ----
    auto stage = [&](int s0, int buf) {
        const unsigned short* kt = Kbase + (size_t)s0 * 64;
        unsigned short* kd = &Ks[buf][0] + (wid << 9);
        gl16(kt + tid * 8, kd);
        gl16(kt + 2048 + tid * 8, kd + 2048);
        const unsigned short* vt = Vbase + s0;
        unsigned short* vd = &Vs[buf][0] + (wid << 9);
        gl16(vt + (size_t)(tid >> 3) * T_PAD + (tid & 7) * 8, vd);
        gl16(vt + (size_t)((tid >> 3) + 32) * T_PAD + (tid & 7) * 8, vd + 2048);
    };

    auto load_hm = [&](int s0, float* hv, float* mv) {
#pragma unroll
        for (int nt = 0; nt < 4; ++nt) {
            int s = s0 + nt * 16 + l15;
#pragma unroll
            for (int r = 0; r < 4; ++r) {
                int t = t0 + g * 4 + r;
                int tc = t > 826 ? 826 : t;
                int scl = s > tc ? tc : s;
                hv[nt * 4 + r] = hb[(size_t)tc * T_SEQ + scl];
            }
        }
        bool hasmask = (s0 < 256 && (t0 + 15) >= 285) ||
                       ((s0 + 63) >= 286 && s0 < 542 && (t0 + 15) >= 571);
        if (hasmask) {
#pragma unroll
            for (int nt = 0; nt < 4; ++nt) {
                int s = s0 + nt * 16 + l15;
#pragma unroll
                for (int r = 0; r < 4; ++r) {
                    int t = t0 + g * 4 + r;
                    bool in1 = (s < 256) & (t >= 285) & (t < 541);
                    bool in2 = (s < 256) & (t >= 571);
                    bool in3 = (s >= 286) & (s < 542) & (t >= 571);
                    bool any = in1 | in2 | in3;
                    int base = in1 ? 0 : (in2 ? 262144 : 524288);
                    int tt = in1 ? (t - 285) : (t - 571);
                    int ss = in3 ? (s - 286) : s;
                    int idx = base + b * 65536 + tt * 256 + ss;
                    idx = any ? idx : 0;
                    float mval = maskp[idx];
                    mv[nt * 4 + r] = any ? mval : 1.0f;
                }
            }
        } else {
#pragma unroll
            for (int i = 0; i < 16; ++i) mv[i] = 1.0f;
        }
    };

    float hc[16], mc[16], hn[16], mn_[16];
    load_hm(0, hc, mc);
    stage(0, 0);

    for (int it = 0; it < ntiles; ++it) {
        int cur = it & 1;
        int s0 = it * 64;
        bool more = (it + 1 < ntiles);
        __syncthreads();                       // stage(it) complete (barrier drains vmcnt)
        if (more) {
            stage(s0 + 64, cur ^ 1);           // overlaps with this tile's compute
            load_hm(s0 + 64, hn, mn_);         // register-prefetch next h/mask
        }

        // ---- QK^T from swizzled Ks[cur] ----
        facc4 sfa[4] = {};
#pragma unroll
        for (int nt = 0; nt < 4; ++nt) {
            int row = nt * 16 + l15;
            const unsigned short* kp = &Ks[cur][row * 64];
            bfrag8 k0 = *reinterpret_cast<const bfrag8*>(kp + ((g ^ (row & 7)) << 3));
            bfrag8 k1 = *reinterpret_cast<const bfrag8*>(kp + (((4 + g) ^ (row & 7)) << 3));
            sfa[nt] = MFMA16(aq0, k0, sfa[nt]);
            sfa[nt] = MFMA16(aq1, k1, sfa[nt]);
        }

        // ---- score: bias + mask + causal, row max ----
        float rmax[4];
#pragma unroll
        for (int r = 0; r < 4; ++r) {
            int t = t0 + g * 4 + r;
            float rm = NEG_INF;
#pragma unroll
            for (int nt = 0; nt < 4; ++nt) {
                int s = s0 + nt * 16 + l15;
                float v = sfa[nt][r] * 0.125f + hc[nt * 4 + r];
                v *= mc[nt * 4 + r];
                v = ((t < T_SEQ) && (s <= t)) ? v : NEG_INF;
                sfa[nt][r] = v;
                rm = fmaxf(rm, v);
            }
#pragma unroll
            for (int off = 8; off; off >>= 1) rm = fmaxf(rm, __shfl_xor(rm, off));
            rmax[r] = rm;
        }

        // ---- online softmax update + P store (swizzled) ----
#pragma unroll
        for (int r = 0; r < 4; ++r) {
            float mnew = fmaxf(m_r[r], rmax[r]);
            float scale = __expf(m_r[r] - mnew);
            float ps = 0.f;
            int rr = g * 4 + r;
#pragma unroll
            for (int nt = 0; nt < 4; ++nt) {
                float p = __expf(sfa[nt][r] - mnew);
                ps += p;
                pw[rr * 64 + ((nt * 16 + l15) ^ ((rr & 7) << 3))] = f2bf(p);
            }
#pragma unroll
            for (int off = 8; off; off >>= 1) ps += __shfl_xor(ps, off);
            l_r[r] = l_r[r] * scale + ps;
            m_r[r] = mnew;
#pragma unroll
            for (int dt = 0; dt < 4; ++dt) acc[dt][r] *= scale;
        }

        // ---- PV from swizzled Vs[cur] ----
#pragma unroll
        for (int c = 0; c < 2; ++c) {
            bfrag8 ap = *reinterpret_cast<const bfrag8*>(&pw[l15 * 64 + (((c * 4 + g) ^ (l15 & 7)) << 3)]);
#pragma unroll
            for (int dt = 0; dt < 4; ++dt) {
                int row = dt * 16 + l15;
                bfrag8 vf = *reinterpret_cast<const bfrag8*>(&Vs[cur][row * 64 + (((c * 4 + g) ^ (row & 7)) << 3)]);
                acc[dt] = MFMA16(ap, vf, acc[dt]);
            }
        }

        if (more) {
#pragma unroll
            for (int i = 0; i < 16; ++i) { hc[i] = hn[i]; mc[i] = mn_[i]; }
        }
    }

#pragma unroll
    for (int dt = 0; dt < 4; ++dt)
#pragma unroll
        for (int r = 0; r < 4; ++r) {
            int t = t0 + g * 4 + r;
            if (t < T_SEQ)
                y[((size_t)(b * T_SEQ) + t) * 1024 + hh * 64 + dt * 16 + l15] = f2bf(acc[dt][r] / l_r[r]);
        }
}

extern "C" void kernel_launch(void* const* d_in, const int* in_sizes, int n_in,
                              void* d_out, int out_size, void* d_ws, size_t ws_size,
                              hipStream_t stream) {
    const float* x   = (const float*)d_in[0];
    const float* h   = (const float*)d_in[1];
    const float* f01 = (const float*)d_in[2];
    const float* f02 = (const float*)d_in[3];
    const float* f12 = (const float*)d_in[4];
    const float* b01 = (const float*)d_in[5];
    const float* b02 = (const float*)d_in[6];
    const float* b12 = (const float*)d_in[7];
    const float* Wq  = (const float*)d_in[8];
    const float* bq  = (const float*)d_in[9];
    const float* Wk  = (const float*)d_in[10];
    const float* bk  = (const float*)d_in[11];
    const float* Wv  = (const float*)d_in[12];
    const float* bv  = (const float*)d_in[13];
    const float* Wp  = (const float*)d_in[14];
    const float* bp  = (const float*)d_in[15];

    char* ws = (char*)d_ws;
    float* minmax = (float*)ws;
    float* bl     = (float*)(ws + 256);
    float* masks  = (float*)(ws + 256 + 3145728);
    unsigned short* x_bf  = (unsigned short*)(ws + 256 + 2 * 3145728);
    unsigned short* WtQKV = x_bf + (size_t)3308 * 1024;
    unsigned short* WtP   = WtQKV + (size_t)3072 * 1024;
    unsigned short* q_bf  = WtP + (size_t)1024 * 1024;
    unsigned short* k_bf  = q_bf + (size_t)64 * T_PAD * 64;
    unsigned short* vTb   = k_bf + (size_t)64 * T_PAD * 64;
    unsigned short* y_bf  = vTb  + (size_t)64 * T_PAD * 64;

    k_init<<<1, 64, 0, stream>>>(minmax);
    k_convert<<<3308, 256, 0, stream>>>(x, x_bf);
    dim3 tg(32, 32);
    k_transpose<<<tg, 256, 0, stream>>>(Wq, WtQKV);
    k_transpose<<<tg, 256, 0, stream>>>(Wk, WtQKV + (size_t)1024 * 1024);
    k_transpose<<<tg, 256, 0, stream>>>(Wv, WtQKV + (size_t)2048 * 1024);
    k_transpose<<<tg, 256, 0, stream>>>(Wp, WtP);
    k_blur<<<3072, 256, 0, stream>>>(f01, f02, f12, b01, b02, b12, bl, minmax);
    k_finalize<<<3072, 256, 0, stream>>>(f01, f02, f12, b01, b02, b12, bl, minmax, masks);
    k_zero<<<64, 256, 0, stream>>>(q_bf, k_bf, vTb);

    dim3 gqkv(26, 24);
    k_gemm<0><<<gqkv, 256, 0, stream>>>(x_bf, WtQKV, bq, bk, bv, q_bf, k_bf, vTb, nullptr, 3308);
    k_attn<<<832, 256, 0, stream>>>(q_bf, k_bf, vTb, h, masks, y_bf);
    dim3 gp(26, 8);
    k_gemm<2><<<gp, 256, 0, stream>>>(y_bf, WtP, bp, nullptr, nullptr, nullptr, nullptr, nullptr,
                                      (float*)d_out, 3308);
}

// Round 3
// 221.328 us; speedup vs baseline: 1.7883x; 1.0980x over previous
//
#include <hip/hip_runtime.h>
#include <math.h>

using bfrag8 = __attribute__((ext_vector_type(8))) short;
using facc4  = __attribute__((ext_vector_type(4))) float;

#define MFMA16(a,b,c) __builtin_amdgcn_mfma_f32_16x16x32_bf16((a),(b),(c),0,0,0)

#define T_SEQ 827
#define T_PAD 832
#define NHEAD 16
#define NEG_INF (-__builtin_inff())
#define CM_TOT 1179392   // 4*542*544

static __device__ __forceinline__ unsigned short f2bf(float f) {
    unsigned int x = __float_as_uint(f);
    unsigned int r = x + 0x7FFFu + ((x >> 16) & 1u);
    return (unsigned short)(r >> 16);
}

// global -> LDS async copy, 16B per lane. LDS dest must be wave-uniform base (+lane*16 auto).
static __device__ __forceinline__ void gl16(const unsigned short* g, unsigned short* l) {
    __builtin_amdgcn_global_load_lds(
        (const __attribute__((address_space(1))) unsigned int*)g,
        (__attribute__((address_space(3))) unsigned int*)l,
        16, 0, 0);
}

// ---------------- prep: x->bf16, cm:=1, minmax init, q/k/vT pad zero --------------
__global__ __launch_bounds__(256) void k_prep(const float* __restrict__ x,
                                              unsigned short* __restrict__ x_bf,
                                              float* __restrict__ cm, float* minmax,
                                              unsigned short* q, unsigned short* k,
                                              unsigned short* vT) {
    int bid = blockIdx.x, tid = threadIdx.x;
    if (bid == 0 && tid < 3) {
        ((unsigned int*)minmax)[2 * tid]     = 0x7F800000u; // +inf
        ((unsigned int*)minmax)[2 * tid + 1] = 0u;
    }
    if (bid < 3308) {
        int i = (bid * 256 + tid) * 4;
        float4 v = *reinterpret_cast<const float4*>(x + i);
        ushort4 o;
        o.x = f2bf(v.x); o.y = f2bf(v.y); o.z = f2bf(v.z); o.w = f2bf(v.w);
        *reinterpret_cast<ushort4*>(x_bf + i) = o;
    } else if (bid < 4460) {
        int base = (bid - 3308) * 1024 + tid * 4;
        if (base + 4 <= CM_TOT) {
            float4 one = {1.f, 1.f, 1.f, 1.f};
            *reinterpret_cast<float4*>(cm + base) = one;
        } else {
#pragma unroll
            for (int j = 0; j < 4; ++j)
                if (base + j < CM_TOT) cm[base + j] = 1.f;
        }
    } else {
        int bh = bid - 4460;
        for (int i = tid; i < 320; i += 256) {
            int t = 827 + i / 64, d = i % 64;
            q[((size_t)bh * T_PAD + t) * 64 + d] = 0;
            k[((size_t)bh * T_PAD + t) * 64 + d] = 0;
        }
        for (int i = tid; i < 4096; i += 256) {
            int d = i >> 6, s = 768 + (i & 63);
            vT[((size_t)bh * 64 + d) * T_PAD + s] = 0;
        }
    }
}

// ---------------- 4x W (K x N) -> Wt bf16 (N x K), fused --------------------------
__global__ __launch_bounds__(256) void k_transpose4(const float* __restrict__ Wq,
                                                    const float* __restrict__ Wk,
                                                    const float* __restrict__ Wv,
                                                    const float* __restrict__ Wp,
                                                    unsigned short* __restrict__ out) {
    __shared__ float tile[32][33];
    int z = blockIdx.z;
    const float* W = (z == 0) ? Wq : (z == 1) ? Wk : (z == 2) ? Wv : Wp;
    unsigned short* Wt = out + (size_t)z * 1048576;
    int bx = blockIdx.x, by = blockIdx.y;
    int tx = threadIdx.x & 31, ty0 = threadIdx.x >> 5;
#pragma unroll
    for (int i = 0; i < 4; ++i) {
        int ty = ty0 + i * 8;
        tile[ty][tx] = W[(size_t)(by * 32 + ty) * 1024 + bx * 32 + tx];
    }
    __syncthreads();
#pragma unroll
    for (int i = 0; i < 4; ++i) {
        int ty = ty0 + i * 8;
        Wt[(size_t)(bx * 32 + ty) * 1024 + by * 32 + tx] = f2bf(tile[tx][ty]);
    }
}

// ---------------- blur ------------------------------------------------------------
__global__ __launch_bounds__(256) void k_blur(const float* f01, const float* f02, const float* f12,
                                              const float* b01, const float* b02, const float* b12,
                                              float* __restrict__ bl, float* minmax) {
    int m = blockIdx.x >> 10, rem = blockIdx.x & 1023, b = rem >> 8, r = rem & 255;
    const float* f  = (m == 0) ? f01 : (m == 1) ? f02 : f12;
    const float* bm = (m == 0) ? b01 : (m == 1) ? b02 : b12;
    int tid = threadIdx.x, i = tid >> 4, j = tid & 15;

    float k1[7]; float ks = 0.f;
#pragma unroll
    for (int d = 0; d < 7; ++d) { float hx = (float)d - 3.f; k1[d] = expf(-0.5f * hx * hx / 2.25f); ks += k1[d]; }
#pragma unroll
    for (int d = 0; d < 7; ++d) k1[d] /= ks;

    __shared__ float img[16][17], tmp[16][17];
    size_t idx = (size_t)b * 65536 + (size_t)r * 256 + tid;
    float bi = f[idx] * bm[(size_t)b * 65536 + (size_t)tid * 256 + r];
    img[i][j] = bi;
    __syncthreads();
    float ha = 0.f;
#pragma unroll
    for (int d = 0; d < 7; ++d) { int p = j - 3 + d; p = p < 0 ? -p : (p > 15 ? 30 - p : p); ha += k1[d] * img[i][p]; }
    tmp[i][j] = ha;
    __syncthreads();
    float v = 0.f;
#pragma unroll
    for (int d = 0; d < 7; ++d) { int p = i - 3 + d; p = p < 0 ? -p : (p > 15 ? 30 - p : p); v += k1[d] * tmp[p][j]; }
    bl[(size_t)m * 262144 + idx] = v;

    float mn = v, mx = v;
#pragma unroll
    for (int off = 32; off; off >>= 1) { mn = fminf(mn, __shfl_xor(mn, off)); mx = fmaxf(mx, __shfl_xor(mx, off)); }
    __shared__ float smn[4], smx[4];
    int wid = tid >> 6, lane = tid & 63;
    if (lane == 0) { smn[wid] = mn; smx[wid] = mx; }
    __syncthreads();
    if (tid == 0) {
        mn = fminf(fminf(smn[0], smn[1]), fminf(smn[2], smn[3]));
        mx = fmaxf(fmaxf(smx[0], smx[1]), fmaxf(smx[2], smx[3]));
        atomicMin((int*)minmax + 2 * m,     __float_as_int(mn));
        atomicMax((int*)minmax + 2 * m + 1, __float_as_int(mx));
    }
}

// ---------------- finalize -> combined mask cm[b][542][544] -----------------------
__global__ __launch_bounds__(256) void k_finalize(const float* f01, const float* f02, const float* f12,
                                                  const float* b01, const float* b02, const float* b12,
                                                  const float* __restrict__ bl, const float* minmax,
                                                  float* __restrict__ cm) {
    int m = blockIdx.x >> 10, rem = blockIdx.x & 1023, b = rem >> 8, r = rem & 255;
    const float* f  = (m == 0) ? f01 : (m == 1) ? f02 : f12;
    const float* bm = (m == 0) ? b01 : (m == 1) ? b02 : b12;
    int tid = threadIdx.x;
    size_t idx = (size_t)b * 65536 + (size_t)r * 256 + tid;
    float mn = minmax[2 * m], mx = minmax[2 * m + 1];
    float w = (bl[(size_t)m * 262144 + idx] - mn) / (mx - mn);
    w = fminf(fmaxf(w, 0.f), 1.f);
    float val = w * f[idx] * bm[(size_t)b * 65536 + (size_t)tid * 256 + r];
    int row = (m == 0) ? r : r + 286;
    int col = (m == 2) ? tid + 286 : tid;
    cm[((size_t)b * 542 + row) * 544 + col] = val;
}

// ---------------- GEMM 128x128 tile, BK=32, global_load_lds staging ---------------
template<int MODE>
__global__ __launch_bounds__(256) void k_gemm(const unsigned short* __restrict__ A,
                                              const unsigned short* __restrict__ Bt,
                                              const float* __restrict__ b0, const float* __restrict__ b1,
                                              const float* __restrict__ b2,
                                              unsigned short* __restrict__ qo, unsigned short* __restrict__ ko,
                                              unsigned short* __restrict__ vo, float* __restrict__ fo, int M) {
    __shared__ unsigned short As[4096];
    __shared__ unsigned short Bs[4096];
    int m0 = blockIdx.x * 128, n0 = blockIdx.y * 128;
    int tid = threadIdx.x, wid = tid >> 6, lane = tid & 63;
    int g = lane >> 4, l15 = lane & 15;
    int wm = wid >> 1, wn = wid & 1;
    facc4 acc[4][4] = {};

    int ar0 = m0 + (tid >> 2); if (ar0 > M - 1) ar0 = M - 1;
    int ar1 = m0 + 64 + (tid >> 2); if (ar1 > M - 1) ar1 = M - 1;
    const unsigned short* Ap0 = A + (size_t)ar0 * 1024 + (tid & 3) * 8;
    const unsigned short* Ap1 = A + (size_t)ar1 * 1024 + (tid & 3) * 8;
    const unsigned short* Bp0 = Bt + (size_t)(n0 + (tid >> 2)) * 1024 + (tid & 3) * 8;
    const unsigned short* Bp1 = Bp0 + (size_t)64 * 1024;
    unsigned short* asw = As + (wid << 9);
    unsigned short* bsw = Bs + (wid << 9);

    for (int k0 = 0; k0 < 1024; k0 += 32) {
        if (k0) __syncthreads();
        gl16(Ap0 + k0, asw);
        gl16(Ap1 + k0, asw + 2048);
        gl16(Bp0 + k0, bsw);
        gl16(Bp1 + k0, bsw + 2048);
        __syncthreads();
        bfrag8 af[4], bf[4];
#pragma unroll
        for (int mi = 0; mi < 4; ++mi)
            af[mi] = *reinterpret_cast<const bfrag8*>(&As[(wm * 64 + mi * 16 + l15) * 32 + g * 8]);
#pragma unroll
        for (int ni = 0; ni < 4; ++ni)
            bf[ni] = *reinterpret_cast<const bfrag8*>(&Bs[(wn * 64 + ni * 16 + l15) * 32 + g * 8]);
#pragma unroll
        for (int mi = 0; mi < 4; ++mi)
#pragma unroll
            for (int ni = 0; ni < 4; ++ni)
                acc[mi][ni] = MFMA16(af[mi], bf[ni], acc[mi][ni]);
    }

    int which = n0 >> 10;
    const float* bb = (MODE == 2) ? b0 : (which == 0 ? b0 : (which == 1 ? b1 : b2));
#pragma unroll
    for (int mi = 0; mi < 4; ++mi)
#pragma unroll
        for (int ni = 0; ni < 4; ++ni)
#pragma unroll
            for (int r = 0; r < 4; ++r) {
                int row = m0 + wm * 64 + mi * 16 + g * 4 + r;
                if (row >= M) continue;
                int col = n0 + wn * 64 + ni * 16 + l15;
                float v = acc[mi][ni][r] + bb[col & 1023];
                if (MODE == 2) {
                    fo[(size_t)row * 1024 + col] = v;
                } else {
                    int b = row / T_SEQ, t = row - b * T_SEQ;
                    int cc = col & 1023;
                    int hh = cc >> 6, d = cc & 63;
                    size_t bh = (size_t)(b * NHEAD + hh);
                    if (which == 0) {
                        qo[(bh * T_PAD + t) * 64 + d] = f2bf(v);
                    } else if (which == 1) {
                        int du = (((d >> 3) ^ (t & 7)) << 3) | (d & 7);
                        ko[(bh * T_PAD + t) * 64 + du] = f2bf(v);
                    } else {
                        int sl = t & 63;
                        int su = (((sl >> 3) ^ (d & 7)) << 3) | (t & 7);
                        vo[(bh * 64 + d) * T_PAD + (t - sl) + su] = f2bf(v);
                    }
                }
            }
}

// ---------------- flash attention v3: swapped QK^T, in-register softmax -----------
__global__ __launch_bounds__(256) void k_attn(const unsigned short* __restrict__ qb,
                                              const unsigned short* __restrict__ kb,
                                              const unsigned short* __restrict__ vT,
                                              const float* __restrict__ h,
                                              const float* __restrict__ cm,
                                              unsigned short* __restrict__ y) {
    int blk = blockIdx.x;
    int bh = blk / 13;
    int qt = 12 - (blk % 13);       // long blocks first
    int b = bh >> 4, hh = bh & 15;
    int tid = threadIdx.x, wid = tid >> 6, lane = tid & 63;
    int g = lane >> 4, l15 = lane & 15;
    int t0 = qt * 64 + wid * 16;
    int t = t0 + l15;               // this lane's t-column
    int tcl = t > 826 ? 826 : t;
    int ntiles = qt + 1;

    __shared__ unsigned short Ks[2][4096];
    __shared__ unsigned short Vs[2][4096];
    __shared__ unsigned short Ps[4][1024];
    unsigned short* pw = &Ps[wid][0];

    const unsigned short* Kbase = kb + (size_t)bh * T_PAD * 64;
    const unsigned short* Vbase = vT + (size_t)bh * 64 * T_PAD;
    const float* hrow = h + (size_t)bh * T_SEQ * T_SEQ + (size_t)tcl * T_SEQ;
    int rt = t - 285; rt = rt < 0 ? 0 : (rt > 541 ? 541 : rt);
    const float* cmrow = cm + ((size_t)b * 542 + rt) * 544;
    bool tm = (t >= 285);

    // Q fragments (B-operand; lane l15 = t-column)
    size_t qrow = ((size_t)bh * T_PAD + t) * 64 + g * 8;
    bfrag8 aq0 = *reinterpret_cast<const bfrag8*>(qb + qrow);
    bfrag8 aq1 = *reinterpret_cast<const bfrag8*>(qb + qrow + 32);

    auto stage = [&](int s0, int buf) {
        const unsigned short* kt = Kbase + (size_t)s0 * 64;
        unsigned short* kd = &Ks[buf][0] + (wid << 9);
        gl16(kt + tid * 8, kd);
        gl16(kt + 2048 + tid * 8, kd + 2048);
        const unsigned short* vt = Vbase + s0;
        unsigned short* vd = &Vs[buf][0] + (wid << 9);
        gl16(vt + (size_t)(tid >> 3) * T_PAD + (tid & 7) * 8, vd);
        gl16(vt + (size_t)((tid >> 3) + 32) * T_PAD + (tid & 7) * 8, vd + 2048);
    };

    auto loadh = [&](int s0t, float* hv, float* mv) {
#pragma unroll
        for (int nt = 0; nt < 4; ++nt) {
            int sb = s0t + nt * 16 + 4 * g;
            float h4[4];
            if (sb + 3 <= tcl) {
                __builtin_memcpy(h4, hrow + sb, 16);
            } else {
#pragma unroll
                for (int j = 0; j < 4; ++j) {
                    float hx = 0.f;
                    if (sb + j <= tcl) hx = hrow[sb + j];
                    h4[j] = hx;
                }
            }
            float m4[4];
            if (tm && sb <= 540) {
                __builtin_memcpy(m4, cmrow + sb, 16);
            } else {
#pragma unroll
                for (int j = 0; j < 4; ++j) m4[j] = 1.f;
            }
#pragma unroll
            for (int j = 0; j < 4; ++j) { hv[nt * 4 + j] = h4[j]; mv[nt * 4 + j] = m4[j]; }
        }
    };

    float m_r = NEG_INF, l_r = 0.f;
    facc4 acc[4] = {};
    float hv[16], mv[16];
    loadh(0, hv, mv);
    stage(0, 0);

    for (int it = 0; it < ntiles; ++it) {
        int cur = it & 1, s0 = it * 64;
        bool more = (it + 1 < ntiles);
        bool diag = !more;                 // last tile contains the diagonal
        __syncthreads();                   // stage(it) complete
        if (more) stage(s0 + 64, cur ^ 1);

        // ---- QK^T (swapped: A=K, B=Q) -> lane holds S[s=s0+nt*16+4g+r][t] ----
        facc4 sf[4] = {};
#pragma unroll
        for (int nt = 0; nt < 4; ++nt) {
            int row = nt * 16 + l15;
            const unsigned short* kp = &Ks[cur][row * 64];
            bfrag8 k0 = *reinterpret_cast<const bfrag8*>(kp + ((g ^ (row & 7)) << 3));
            bfrag8 k1 = *reinterpret_cast<const bfrag8*>(kp + (((4 + g) ^ (row & 7)) << 3));
            sf[nt] = MFMA16(k0, aq0, sf[nt]);
            sf[nt] = MFMA16(k1, aq1, sf[nt]);
        }

        // ---- score + in-register partial max ----
        float vmax = NEG_INF;
#pragma unroll
        for (int nt = 0; nt < 4; ++nt)
#pragma unroll
            for (int r = 0; r < 4; ++r) {
                float val = fmaf(sf[nt][r], 0.125f, hv[nt * 4 + r]) * mv[nt * 4 + r];
                if (diag) {
                    int s = s0 + nt * 16 + 4 * g + r;
                    val = (s <= tcl) ? val : NEG_INF;
                }
                sf[nt][r] = val;
                vmax = fmaxf(vmax, val);
            }

        if (more) loadh(s0 + 64, hv, mv);  // prefetch next tile's h/mask

        vmax = fmaxf(vmax, __shfl_xor(vmax, 16));
        vmax = fmaxf(vmax, __shfl_xor(vmax, 32));
        float mnew = fmaxf(m_r, vmax);

        float ps = 0.f;
#pragma unroll
        for (int nt = 0; nt < 4; ++nt)
#pragma unroll
            for (int r = 0; r < 4; ++r) {
                float p = __expf(sf[nt][r] - mnew);
                sf[nt][r] = p;
                ps += p;
            }
        ps += __shfl_xor(ps, 16);
        ps += __shfl_xor(ps, 32);

        // ---- pack P (bf16) -> LDS [t][s] swizzled ----
#pragma unroll
        for (int nt = 0; nt < 4; ++nt) {
            unsigned u0, u1;
            asm("v_cvt_pk_bf16_f32 %0, %1, %2" : "=v"(u0) : "v"(sf[nt][0]), "v"(sf[nt][1]));
            asm("v_cvt_pk_bf16_f32 %0, %1, %2" : "=v"(u1) : "v"(sf[nt][2]), "v"(sf[nt][3]));
            int el = (l15 * 64 + nt * 16 + 4 * g) ^ ((l15 & 7) << 3);
            uint2 uu; uu.x = u0; uu.y = u1;
            *reinterpret_cast<uint2*>(&pw[el]) = uu;
        }

        // ---- online-softmax state update (skip rescale when max unchanged) ----
        if (__any(mnew > m_r)) {
            float scale = __expf(m_r - mnew);
            l_r = l_r * scale + ps;
#pragma unroll
            for (int r = 0; r < 4; ++r) {
                float sc = __int_as_float(__builtin_amdgcn_ds_bpermute((4 * g + r) * 4, __float_as_int(scale)));
#pragma unroll
                for (int dt = 0; dt < 4; ++dt) acc[dt][r] *= sc;
            }
        } else {
            l_r += ps;
        }
        m_r = mnew;

        // ---- PV: A=P (LDS), B=V^T (LDS) ----
#pragma unroll
        for (int c2 = 0; c2 < 2; ++c2) {
            int ela = (l15 * 64 + c2 * 32 + 8 * g) ^ ((l15 & 7) << 3);
            bfrag8 ap = *reinterpret_cast<const bfrag8*>(&pw[ela]);
#pragma unroll
            for (int dt = 0; dt < 4; ++dt) {
                int row = dt * 16 + l15;
                bfrag8 vf = *reinterpret_cast<const bfrag8*>(&Vs[cur][row * 64 + (((c2 * 4 + g) ^ (row & 7)) << 3)]);
                acc[dt] = MFMA16(ap, vf, acc[dt]);
            }
        }
    }

    float linv = 1.0f / l_r;
#pragma unroll
    for (int r = 0; r < 4; ++r) {
        float li = __int_as_float(__builtin_amdgcn_ds_bpermute((4 * g + r) * 4, __float_as_int(linv)));
        int tt = t0 + 4 * g + r;
        if (tt < T_SEQ) {
#pragma unroll
            for (int dt = 0; dt < 4; ++dt)
                y[((size_t)(b * T_SEQ) + tt) * 1024 + hh * 64 + dt * 16 + l15] = f2bf(acc[dt][r] * li);
        }
    }
}

extern "C" void kernel_launch(void* const* d_in, const int* in_sizes, int n_in,
                              void* d_out, int out_size, void* d_ws, size_t ws_size,
                              hipStream_t stream) {
    const float* x   = (const float*)d_in[0];
    const float* h   = (const float*)d_in[1];
    const float* f01 = (const float*)d_in[2];
    const float* f02 = (const float*)d_in[3];
    const float* f12 = (const float*)d_in[4];
    const float* b01 = (const float*)d_in[5];
    const float* b02 = (const float*)d_in[6];
    const float* b12 = (const float*)d_in[7];
    const float* Wq  = (const float*)d_in[8];
    const float* bq  = (const float*)d_in[9];
    const float* Wk  = (const float*)d_in[10];
    const float* bk  = (const float*)d_in[11];
    const float* Wv  = (const float*)d_in[12];
    const float* bv  = (const float*)d_in[13];
    const float* Wp  = (const float*)d_in[14];
    const float* bp  = (const float*)d_in[15];

    char* ws = (char*)d_ws;
    float* minmax = (float*)ws;
    float* bl     = (float*)(ws + 256);
    float* cmb    = (float*)(ws + 256 + 3145728);
    unsigned short* x_bf  = (unsigned short*)(ws + 256 + 3145728 + 4717568);
    unsigned short* WtQKV = x_bf + (size_t)3308 * 1024;
    unsigned short* WtP   = WtQKV + (size_t)3072 * 1024;
    unsigned short* q_bf  = WtP + (size_t)1024 * 1024;
    unsigned short* k_bf  = q_bf + (size_t)64 * T_PAD * 64;
    unsigned short* vTb   = k_bf + (size_t)64 * T_PAD * 64;
    unsigned short* y_bf  = vTb  + (size_t)64 * T_PAD * 64;

    k_prep<<<4524, 256, 0, stream>>>(x, x_bf, cmb, minmax, q_bf, k_bf, vTb);
    dim3 tg(32, 32, 4);
    k_transpose4<<<tg, 256, 0, stream>>>(Wq, Wk, Wv, Wp, WtQKV);
    k_blur<<<3072, 256, 0, stream>>>(f01, f02, f12, b01, b02, b12, bl, minmax);
    k_finalize<<<3072, 256, 0, stream>>>(f01, f02, f12, b01, b02, b12, bl, minmax, cmb);

    dim3 gqkv(26, 24);
    k_gemm<0><<<gqkv, 256, 0, stream>>>(x_bf, WtQKV, bq, bk, bv, q_bf, k_bf, vTb, nullptr, 3308);
    k_attn<<<832, 256, 0, stream>>>(q_bf, k_bf, vTb, h, cmb, y_bf);
    dim3 gp(26, 8);
    k_gemm<2><<<gp, 256, 0, stream>>>(y_bf, WtP, bp, nullptr, nullptr, nullptr, nullptr, nullptr,
                                      (float*)d_out, 3308);
}

// Round 4
// 153.105 us; speedup vs baseline: 2.5852x; 1.4456x over previous
//
#include <hip/hip_runtime.h>
#include <math.h>

using bfrag8 = __attribute__((ext_vector_type(8))) short;
using facc4  = __attribute__((ext_vector_type(4))) float;

#define MFMA16(a,b,c) __builtin_amdgcn_mfma_f32_16x16x32_bf16((a),(b),(c),0,0,0)

#define T_SEQ 827
#define T_PAD 832
#define NHEAD 16
#define NEG_INF (-__builtin_inff())
#define CM_TOT 1179392   // 4*542*544

static __device__ __forceinline__ unsigned short f2bf(float f) {
    unsigned int x = __float_as_uint(f);
    unsigned int r = x + 0x7FFFu + ((x >> 16) & 1u);
    return (unsigned short)(r >> 16);
}

// global -> LDS async copy, 16B per lane. LDS dest must be wave-uniform base (+lane*16 auto).
static __device__ __forceinline__ void gl16(const unsigned short* g, unsigned short* l) {
    __builtin_amdgcn_global_load_lds(
        (const __attribute__((address_space(1))) unsigned int*)g,
        (__attribute__((address_space(3))) unsigned int*)l,
        16, 0, 0);
}

// ---------------- fused front: x->bf16 | cm:=1 | qkv pads | W transpose | blur ----
// block ranges: [0,3308) convert, [3308,4460) cm ones, [4460,4524) pads,
//               [4524,8620) transpose4, [8620,11692) blur (writes pmm partials)
__global__ __launch_bounds__(256) void k_front(const float* __restrict__ x,
                                               unsigned short* __restrict__ x_bf,
                                               float* __restrict__ cm,
                                               unsigned short* q, unsigned short* k,
                                               unsigned short* vT,
                                               const float* __restrict__ Wq,
                                               const float* __restrict__ Wk,
                                               const float* __restrict__ Wv,
                                               const float* __restrict__ Wp,
                                               unsigned short* __restrict__ Wt_out,
                                               const float* f01, const float* f02, const float* f12,
                                               const float* b01, const float* b02, const float* b12,
                                               float* __restrict__ bl,
                                               float* __restrict__ pmm) {
    __shared__ float tile[32][33];
    __shared__ float img[16][17], tmp[16][17];
    __shared__ float smn[4], smx[4];
    int bid = blockIdx.x, tid = threadIdx.x;

    if (bid < 3308) {
        int i = (bid * 256 + tid) * 4;
        float4 v = *reinterpret_cast<const float4*>(x + i);
        ushort4 o;
        o.x = f2bf(v.x); o.y = f2bf(v.y); o.z = f2bf(v.z); o.w = f2bf(v.w);
        *reinterpret_cast<ushort4*>(x_bf + i) = o;
    } else if (bid < 4460) {
        int base = (bid - 3308) * 1024 + tid * 4;
        if (base + 4 <= CM_TOT) {
            float4 one = {1.f, 1.f, 1.f, 1.f};
            *reinterpret_cast<float4*>(cm + base) = one;
        } else {
#pragma unroll
            for (int j = 0; j < 4; ++j)
                if (base + j < CM_TOT) cm[base + j] = 1.f;
        }
    } else if (bid < 4524) {
        int bh = bid - 4460;
        for (int i = tid; i < 320; i += 256) {
            int t = 827 + i / 64, d = i % 64;
            q[((size_t)bh * T_PAD + t) * 64 + d] = 0;
            k[((size_t)bh * T_PAD + t) * 64 + d] = 0;
        }
        for (int i = tid; i < 4096; i += 256) {
            int d = i >> 6, s = 768 + (i & 63);
            vT[((size_t)bh * 64 + d) * T_PAD + s] = 0;
        }
    } else if (bid < 8620) {
        int i = bid - 4524;
        int z = i >> 10, rem = i & 1023;
        int bx = rem & 31, by = rem >> 5;
        const float* W = (z == 0) ? Wq : (z == 1) ? Wk : (z == 2) ? Wv : Wp;
        unsigned short* Wt = Wt_out + (size_t)z * 1048576;
        int tx = tid & 31, ty0 = tid >> 5;
#pragma unroll
        for (int j = 0; j < 4; ++j) {
            int ty = ty0 + j * 8;
            tile[ty][tx] = W[(size_t)(by * 32 + ty) * 1024 + bx * 32 + tx];
        }
        __syncthreads();
#pragma unroll
        for (int j = 0; j < 4; ++j) {
            int ty = ty0 + j * 8;
            Wt[(size_t)(bx * 32 + ty) * 1024 + by * 32 + tx] = f2bf(tile[tx][ty]);
        }
    } else {
        int i = bid - 8620;
        int m = i >> 10, rem = i & 1023, b = rem >> 8, r = rem & 255;
        const float* f  = (m == 0) ? f01 : (m == 1) ? f02 : f12;
        const float* bm = (m == 0) ? b01 : (m == 1) ? b02 : b12;
        int ii = tid >> 4, j = tid & 15;

        float k1[7]; float ks = 0.f;
#pragma unroll
        for (int d = 0; d < 7; ++d) { float hx = (float)d - 3.f; k1[d] = expf(-0.5f * hx * hx / 2.25f); ks += k1[d]; }
#pragma unroll
        for (int d = 0; d < 7; ++d) k1[d] /= ks;

        size_t idx = (size_t)b * 65536 + (size_t)r * 256 + tid;
        float bi = f[idx] * bm[(size_t)b * 65536 + (size_t)tid * 256 + r];
        img[ii][j] = bi;
        __syncthreads();
        float ha = 0.f;
#pragma unroll
        for (int d = 0; d < 7; ++d) { int p = j - 3 + d; p = p < 0 ? -p : (p > 15 ? 30 - p : p); ha += k1[d] * img[ii][p]; }
        tmp[ii][j] = ha;
        __syncthreads();
        float v = 0.f;
#pragma unroll
        for (int d = 0; d < 7; ++d) { int p = ii - 3 + d; p = p < 0 ? -p : (p > 15 ? 30 - p : p); v += k1[d] * tmp[p][j]; }
        bl[(size_t)m * 262144 + idx] = v;

        float mn = v, mx = v;
#pragma unroll
        for (int off = 32; off; off >>= 1) { mn = fminf(mn, __shfl_xor(mn, off)); mx = fmaxf(mx, __shfl_xor(mx, off)); }
        int wid = tid >> 6, lane = tid & 63;
        if (lane == 0) { smn[wid] = mn; smx[wid] = mx; }
        __syncthreads();
        if (tid == 0) {
            mn = fminf(fminf(smn[0], smn[1]), fminf(smn[2], smn[3]));
            mx = fmaxf(fmaxf(smx[0], smx[1]), fmaxf(smx[2], smx[3]));
            pmm[2 * i]     = mn;    // plain stores, no atomics
            pmm[2 * i + 1] = mx;
        }
    }
}

// ---------------- reduce per-block partials -> minmax[6] (one block per map) ------
__global__ __launch_bounds__(256) void k_reduce6(const float* __restrict__ pmm,
                                                 float* __restrict__ minmax) {
    int m = blockIdx.x, tid = threadIdx.x;
    float mn = __builtin_inff(), mx = 0.f;
    for (int k = tid; k < 1024; k += 256) {
        int e = m * 1024 + k;
        mn = fminf(mn, pmm[2 * e]);
        mx = fmaxf(mx, pmm[2 * e + 1]);
    }
#pragma unroll
    for (int off = 32; off; off >>= 1) { mn = fminf(mn, __shfl_xor(mn, off)); mx = fmaxf(mx, __shfl_xor(mx, off)); }
    __shared__ float smn[4], smx[4];
    int wid = tid >> 6, lane = tid & 63;
    if (lane == 0) { smn[wid] = mn; smx[wid] = mx; }
    __syncthreads();
    if (tid == 0) {
        mn = fminf(fminf(smn[0], smn[1]), fminf(smn[2], smn[3]));
        mx = fmaxf(fmaxf(smx[0], smx[1]), fmaxf(smx[2], smx[3]));
        minmax[2 * m] = mn; minmax[2 * m + 1] = mx;
    }
}

// ---------------- finalize -> combined mask cm[b][542][544] -----------------------
__global__ __launch_bounds__(256) void k_finalize(const float* f01, const float* f02, const float* f12,
                                                  const float* b01, const float* b02, const float* b12,
                                                  const float* __restrict__ bl, const float* minmax,
                                                  float* __restrict__ cm) {
    int m = blockIdx.x >> 10, rem = blockIdx.x & 1023, b = rem >> 8, r = rem & 255;
    const float* f  = (m == 0) ? f01 : (m == 1) ? f02 : f12;
    const float* bm = (m == 0) ? b01 : (m == 1) ? b02 : b12;
    int tid = threadIdx.x;
    size_t idx = (size_t)b * 65536 + (size_t)r * 256 + tid;
    float mn = minmax[2 * m], mx = minmax[2 * m + 1];
    float w = (bl[(size_t)m * 262144 + idx] - mn) / (mx - mn);
    w = fminf(fmaxf(w, 0.f), 1.f);
    float val = w * f[idx] * bm[(size_t)b * 65536 + (size_t)tid * 256 + r];
    int row = (m == 0) ? r : r + 286;
    int col = (m == 2) ? tid + 286 : tid;
    cm[((size_t)b * 542 + row) * 544 + col] = val;
}

// ---------------- GEMM 128x128 tile, BK=32, global_load_lds staging ---------------
template<int MODE>
__global__ __launch_bounds__(256) void k_gemm(const unsigned short* __restrict__ A,
                                              const unsigned short* __restrict__ Bt,
                                              const float* __restrict__ b0, const float* __restrict__ b1,
                                              const float* __restrict__ b2,
                                              unsigned short* __restrict__ qo, unsigned short* __restrict__ ko,
                                              unsigned short* __restrict__ vo, float* __restrict__ fo, int M) {
    __shared__ unsigned short As[4096];
    __shared__ unsigned short Bs[4096];
    int m0 = blockIdx.x * 128, n0 = blockIdx.y * 128;
    int tid = threadIdx.x, wid = tid >> 6, lane = tid & 63;
    int g = lane >> 4, l15 = lane & 15;
    int wm = wid >> 1, wn = wid & 1;
    facc4 acc[4][4] = {};

    int ar0 = m0 + (tid >> 2); if (ar0 > M - 1) ar0 = M - 1;
    int ar1 = m0 + 64 + (tid >> 2); if (ar1 > M - 1) ar1 = M - 1;
    const unsigned short* Ap0 = A + (size_t)ar0 * 1024 + (tid & 3) * 8;
    const unsigned short* Ap1 = A + (size_t)ar1 * 1024 + (tid & 3) * 8;
    const unsigned short* Bp0 = Bt + (size_t)(n0 + (tid >> 2)) * 1024 + (tid & 3) * 8;
    const unsigned short* Bp1 = Bp0 + (size_t)64 * 1024;
    unsigned short* asw = As + (wid << 9);
    unsigned short* bsw = Bs + (wid << 9);

    for (int k0 = 0; k0 < 1024; k0 += 32) {
        if (k0) __syncthreads();
        gl16(Ap0 + k0, asw);
        gl16(Ap1 + k0, asw + 2048);
        gl16(Bp0 + k0, bsw);
        gl16(Bp1 + k0, bsw + 2048);
        __syncthreads();
        bfrag8 af[4], bf[4];
#pragma unroll
        for (int mi = 0; mi < 4; ++mi)
            af[mi] = *reinterpret_cast<const bfrag8*>(&As[(wm * 64 + mi * 16 + l15) * 32 + g * 8]);
#pragma unroll
        for (int ni = 0; ni < 4; ++ni)
            bf[ni] = *reinterpret_cast<const bfrag8*>(&Bs[(wn * 64 + ni * 16 + l15) * 32 + g * 8]);
#pragma unroll
        for (int mi = 0; mi < 4; ++mi)
#pragma unroll
            for (int ni = 0; ni < 4; ++ni)
                acc[mi][ni] = MFMA16(af[mi], bf[ni], acc[mi][ni]);
    }

    int which = n0 >> 10;
    const float* bb = (MODE == 2) ? b0 : (which == 0 ? b0 : (which == 1 ? b1 : b2));
#pragma unroll
    for (int mi = 0; mi < 4; ++mi)
#pragma unroll
        for (int ni = 0; ni < 4; ++ni)
#pragma unroll
            for (int r = 0; r < 4; ++r) {
                int row = m0 + wm * 64 + mi * 16 + g * 4 + r;
                if (row >= M) continue;
                int col = n0 + wn * 64 + ni * 16 + l15;
                float v = acc[mi][ni][r] + bb[col & 1023];
                if (MODE == 2) {
                    fo[(size_t)row * 1024 + col] = v;
                } else {
                    int b = row / T_SEQ, t = row - b * T_SEQ;
                    int cc = col & 1023;
                    int hh = cc >> 6, d = cc & 63;
                    size_t bh = (size_t)(b * NHEAD + hh);
                    if (which == 0) {
                        qo[(bh * T_PAD + t) * 64 + d] = f2bf(v);
                    } else if (which == 1) {
                        int du = (((d >> 3) ^ (t & 7)) << 3) | (d & 7);
                        ko[(bh * T_PAD + t) * 64 + du] = f2bf(v);
                    } else {
                        int sl = t & 63;
                        int su = (((sl >> 3) ^ (d & 7)) << 3) | (t & 7);
                        vo[(bh * 64 + d) * T_PAD + (t - sl) + su] = f2bf(v);
                    }
                }
            }
}

// ---------------- flash attention v3: swapped QK^T, in-register softmax -----------
__global__ __launch_bounds__(256) void k_attn(const unsigned short* __restrict__ qb,
                                              const unsigned short* __restrict__ kb,
                                              const unsigned short* __restrict__ vT,
                                              const float* __restrict__ h,
                                              const float* __restrict__ cm,
                                              unsigned short* __restrict__ y) {
    int blk = blockIdx.x;
    int bh = blk / 13;
    int qt = 12 - (blk % 13);       // long blocks first
    int b = bh >> 4, hh = bh & 15;
    int tid = threadIdx.x, wid = tid >> 6, lane = tid & 63;
    int g = lane >> 4, l15 = lane & 15;
    int t0 = qt * 64 + wid * 16;
    int t = t0 + l15;               // this lane's t-column
    int tcl = t > 826 ? 826 : t;
    int ntiles = qt + 1;

    __shared__ unsigned short Ks[2][4096];
    __shared__ unsigned short Vs[2][4096];
    __shared__ unsigned short Ps[4][1024];
    unsigned short* pw = &Ps[wid][0];

    const unsigned short* Kbase = kb + (size_t)bh * T_PAD * 64;
    const unsigned short* Vbase = vT + (size_t)bh * 64 * T_PAD;
    const float* hrow = h + (size_t)bh * T_SEQ * T_SEQ + (size_t)tcl * T_SEQ;
    int rt = t - 285; rt = rt < 0 ? 0 : (rt > 541 ? 541 : rt);
    const float* cmrow = cm + ((size_t)b * 542 + rt) * 544;
    bool tm = (t >= 285);

    // Q fragments (B-operand; lane l15 = t-column)
    size_t qrow = ((size_t)bh * T_PAD + t) * 64 + g * 8;
    bfrag8 aq0 = *reinterpret_cast<const bfrag8*>(qb + qrow);
    bfrag8 aq1 = *reinterpret_cast<const bfrag8*>(qb + qrow + 32);

    auto stage = [&](int s0, int buf) {
        const unsigned short* kt = Kbase + (size_t)s0 * 64;
        unsigned short* kd = &Ks[buf][0] + (wid << 9);
        gl16(kt + tid * 8, kd);
        gl16(kt + 2048 + tid * 8, kd + 2048);
        const unsigned short* vt = Vbase + s0;
        unsigned short* vd = &Vs[buf][0] + (wid << 9);
        gl16(vt + (size_t)(tid >> 3) * T_PAD + (tid & 7) * 8, vd);
        gl16(vt + (size_t)((tid >> 3) + 32) * T_PAD + (tid & 7) * 8, vd + 2048);
    };

    auto loadh = [&](int s0t, float* hv, float* mv) {
#pragma unroll
        for (int nt = 0; nt < 4; ++nt) {
            int sb = s0t + nt * 16 + 4 * g;
            float h4[4];
            if (sb + 3 <= tcl) {
                __builtin_memcpy(h4, hrow + sb, 16);
            } else {
#pragma unroll
                for (int j = 0; j < 4; ++j) {
                    float hx = 0.f;
                    if (sb + j <= tcl) hx = hrow[sb + j];
                    h4[j] = hx;
                }
            }
            float m4[4];
            if (tm && sb <= 540) {
                __builtin_memcpy(m4, cmrow + sb, 16);
            } else {
#pragma unroll
                for (int j = 0; j < 4; ++j) m4[j] = 1.f;
            }
#pragma unroll
            for (int j = 0; j < 4; ++j) { hv[nt * 4 + j] = h4[j]; mv[nt * 4 + j] = m4[j]; }
        }
    };

    float m_r = NEG_INF, l_r = 0.f;
    facc4 acc[4] = {};
    float hv[16], mv[16];
    loadh(0, hv, mv);
    stage(0, 0);

    for (int it = 0; it < ntiles; ++it) {
        int cur = it & 1, s0 = it * 64;
        bool more = (it + 1 < ntiles);
        bool diag = !more;                 // last tile contains the diagonal
        __syncthreads();                   // stage(it) complete
        if (more) stage(s0 + 64, cur ^ 1);

        // ---- QK^T (swapped: A=K, B=Q) -> lane holds S[s=s0+nt*16+4g+r][t] ----
        facc4 sf[4] = {};
        __builtin_amdgcn_s_setprio(1);
#pragma unroll
        for (int nt = 0; nt < 4; ++nt) {
            int row = nt * 16 + l15;
            const unsigned short* kp = &Ks[cur][row * 64];
            bfrag8 k0 = *reinterpret_cast<const bfrag8*>(kp + ((g ^ (row & 7)) << 3));
            bfrag8 k1 = *reinterpret_cast<const bfrag8*>(kp + (((4 + g) ^ (row & 7)) << 3));
            sf[nt] = MFMA16(k0, aq0, sf[nt]);
            sf[nt] = MFMA16(k1, aq1, sf[nt]);
        }
        __builtin_amdgcn_s_setprio(0);

        // ---- score + in-register partial max ----
        float vmax = NEG_INF;
#pragma unroll
        for (int nt = 0; nt < 4; ++nt)
#pragma unroll
            for (int r = 0; r < 4; ++r) {
                float val = fmaf(sf[nt][r], 0.125f, hv[nt * 4 + r]) * mv[nt * 4 + r];
                if (diag) {
                    int s = s0 + nt * 16 + 4 * g + r;
                    val = (s <= tcl) ? val : NEG_INF;
                }
                sf[nt][r] = val;
                vmax = fmaxf(vmax, val);
            }

        if (more) loadh(s0 + 64, hv, mv);  // prefetch next tile's h/mask

        vmax = fmaxf(vmax, __shfl_xor(vmax, 16));
        vmax = fmaxf(vmax, __shfl_xor(vmax, 32));
        float mnew = fmaxf(m_r, vmax);

        float ps = 0.f;
#pragma unroll
        for (int nt = 0; nt < 4; ++nt)
#pragma unroll
            for (int r = 0; r < 4; ++r) {
                float p = __expf(sf[nt][r] - mnew);
                sf[nt][r] = p;
                ps += p;
            }
        ps += __shfl_xor(ps, 16);
        ps += __shfl_xor(ps, 32);

        // ---- pack P (bf16) -> LDS [t][s] swizzled ----
#pragma unroll
        for (int nt = 0; nt < 4; ++nt) {
            unsigned u0, u1;
            asm("v_cvt_pk_bf16_f32 %0, %1, %2" : "=v"(u0) : "v"(sf[nt][0]), "v"(sf[nt][1]));
            asm("v_cvt_pk_bf16_f32 %0, %1, %2" : "=v"(u1) : "v"(sf[nt][2]), "v"(sf[nt][3]));
            int el = (l15 * 64 + nt * 16 + 4 * g) ^ ((l15 & 7) << 3);
            uint2 uu; uu.x = u0; uu.y = u1;
            *reinterpret_cast<uint2*>(&pw[el]) = uu;
        }

        // ---- online-softmax state update (skip rescale when max unchanged) ----
        if (__any(mnew > m_r)) {
            float scale = __expf(m_r - mnew);
            l_r = l_r * scale + ps;
#pragma unroll
            for (int r = 0; r < 4; ++r) {
                float sc = __int_as_float(__builtin_amdgcn_ds_bpermute((4 * g + r) * 4, __float_as_int(scale)));
#pragma unroll
                for (int dt = 0; dt < 4; ++dt) acc[dt][r] *= sc;
            }
        } else {
            l_r += ps;
        }
        m_r = mnew;

        // ---- PV: A=P (LDS), B=V^T (LDS) ----
        __builtin_amdgcn_s_setprio(1);
#pragma unroll
        for (int c2 = 0; c2 < 2; ++c2) {
            int ela = (l15 * 64 + c2 * 32 + 8 * g) ^ ((l15 & 7) << 3);
            bfrag8 ap = *reinterpret_cast<const bfrag8*>(&pw[ela]);
#pragma unroll
            for (int dt = 0; dt < 4; ++dt) {
                int row = dt * 16 + l15;
                bfrag8 vf = *reinterpret_cast<const bfrag8*>(&Vs[cur][row * 64 + (((c2 * 4 + g) ^ (row & 7)) << 3)]);
                acc[dt] = MFMA16(ap, vf, acc[dt]);
            }
        }
        __builtin_amdgcn_s_setprio(0);
    }

    float linv = 1.0f / l_r;
#pragma unroll
    for (int r = 0; r < 4; ++r) {
        float li = __int_as_float(__builtin_amdgcn_ds_bpermute((4 * g + r) * 4, __float_as_int(linv)));
        int tt = t0 + 4 * g + r;
        if (tt < T_SEQ) {
#pragma unroll
            for (int dt = 0; dt < 4; ++dt)
                y[((size_t)(b * T_SEQ) + tt) * 1024 + hh * 64 + dt * 16 + l15] = f2bf(acc[dt][r] * li);
        }
    }
}

extern "C" void kernel_launch(void* const* d_in, const int* in_sizes, int n_in,
                              void* d_out, int out_size, void* d_ws, size_t ws_size,
                              hipStream_t stream) {
    const float* x   = (const float*)d_in[0];
    const float* h   = (const float*)d_in[1];
    const float* f01 = (const float*)d_in[2];
    const float* f02 = (const float*)d_in[3];
    const float* f12 = (const float*)d_in[4];
    const float* b01 = (const float*)d_in[5];
    const float* b02 = (const float*)d_in[6];
    const float* b12 = (const float*)d_in[7];
    const float* Wq  = (const float*)d_in[8];
    const float* bq  = (const float*)d_in[9];
    const float* Wk  = (const float*)d_in[10];
    const float* bk  = (const float*)d_in[11];
    const float* Wv  = (const float*)d_in[12];
    const float* bv  = (const float*)d_in[13];
    const float* Wp  = (const float*)d_in[14];
    const float* bp  = (const float*)d_in[15];

    char* ws = (char*)d_ws;
    float* minmax = (float*)ws;                       // 256 B
    float* pmm    = (float*)(ws + 256);               // 3072*2*4 = 24576 B
    float* bl     = (float*)(ws + 256 + 24576);       // 3 MB
    float* cmb    = (float*)(ws + 256 + 24576 + 3145728);  // 4.7 MB
    unsigned short* x_bf  = (unsigned short*)(ws + 256 + 24576 + 3145728 + 4717568);
    unsigned short* WtQKV = x_bf + (size_t)3308 * 1024;
    unsigned short* WtP   = WtQKV + (size_t)3072 * 1024;
    unsigned short* q_bf  = WtP + (size_t)1024 * 1024;
    unsigned short* k_bf  = q_bf + (size_t)64 * T_PAD * 64;
    unsigned short* vTb   = k_bf + (size_t)64 * T_PAD * 64;
    unsigned short* y_bf  = vTb  + (size_t)64 * T_PAD * 64;

    k_front<<<11692, 256, 0, stream>>>(x, x_bf, cmb, q_bf, k_bf, vTb,
                                       Wq, Wk, Wv, Wp, WtQKV,
                                       f01, f02, f12, b01, b02, b12, bl, pmm);
    k_reduce6<<<3, 256, 0, stream>>>(pmm, minmax);
    k_finalize<<<3072, 256, 0, stream>>>(f01, f02, f12, b01, b02, b12, bl, minmax, cmb);

    dim3 gqkv(26, 24);
    k_gemm<0><<<gqkv, 256, 0, stream>>>(x_bf, WtQKV, bq, bk, bv, q_bf, k_bf, vTb, nullptr, 3308);
    k_attn<<<832, 256, 0, stream>>>(q_bf, k_bf, vTb, h, cmb, y_bf);
    dim3 gp(26, 8);
    k_gemm<2><<<gp, 256, 0, stream>>>(y_bf, WtP, bp, nullptr, nullptr, nullptr, nullptr, nullptr,
                                      (float*)d_out, 3308);
}

// Round 6
// 142.722 us; speedup vs baseline: 2.7733x; 1.0728x over previous
//
#include <hip/hip_runtime.h>
#include <math.h>

using bfrag8 = __attribute__((ext_vector_type(8))) short;
using facc4  = __attribute__((ext_vector_type(4))) float;

#define MFMA16(a,b,c) __builtin_amdgcn_mfma_f32_16x16x32_bf16((a),(b),(c),0,0,0)

#define T_SEQ 827
#define T_PAD 832
#define NHEAD 16
#define NEG_INF (-__builtin_inff())
#define CM_TOT 1179392   // 4*542*544

static __device__ __forceinline__ unsigned short f2bf(float f) {
    unsigned int x = __float_as_uint(f);
    unsigned int r = x + 0x7FFFu + ((x >> 16) & 1u);
    return (unsigned short)(r >> 16);
}

// global -> LDS async copy, 16B per lane. LDS dest must be wave-uniform base (+lane*16 auto).
static __device__ __forceinline__ void gl16(const unsigned short* g, unsigned short* l) {
    __builtin_amdgcn_global_load_lds(
        (const __attribute__((address_space(1))) unsigned int*)g,
        (__attribute__((address_space(3))) unsigned int*)l,
        16, 0, 0);
}

// ---------------- fused front: x->bf16 | cm:=1 | qkv pads | W transpose | blur ----
// block ranges: [0,3308) convert, [3308,4460) cm ones, [4460,4524) pads,
//               [4524,8620) transpose4, [8620,11692) blur (writes pmm partials)
__global__ __launch_bounds__(256) void k_front(const float* __restrict__ x,
                                               unsigned short* __restrict__ x_bf,
                                               float* __restrict__ cm,
                                               unsigned short* q, unsigned short* k,
                                               unsigned short* vT,
                                               const float* __restrict__ Wq,
                                               const float* __restrict__ Wk,
                                               const float* __restrict__ Wv,
                                               const float* __restrict__ Wp,
                                               unsigned short* __restrict__ Wt_out,
                                               const float* f01, const float* f02, const float* f12,
                                               const float* b01, const float* b02, const float* b12,
                                               float* __restrict__ bl,
                                               float* __restrict__ pmm) {
    __shared__ float tile[32][33];
    __shared__ float img[16][17], tmp[16][17];
    __shared__ float smn[4], smx[4];
    int bid = blockIdx.x, tid = threadIdx.x;

    if (bid < 3308) {
        int i = (bid * 256 + tid) * 4;
        float4 v = *reinterpret_cast<const float4*>(x + i);
        ushort4 o;
        o.x = f2bf(v.x); o.y = f2bf(v.y); o.z = f2bf(v.z); o.w = f2bf(v.w);
        *reinterpret_cast<ushort4*>(x_bf + i) = o;
    } else if (bid < 4460) {
        int base = (bid - 3308) * 1024 + tid * 4;
        if (base + 4 <= CM_TOT) {
            float4 one = {1.f, 1.f, 1.f, 1.f};
            *reinterpret_cast<float4*>(cm + base) = one;
        } else {
#pragma unroll
            for (int j = 0; j < 4; ++j)
                if (base + j < CM_TOT) cm[base + j] = 1.f;
        }
    } else if (bid < 4524) {
        int bh = bid - 4460;
        for (int i = tid; i < 320; i += 256) {
            int t = 827 + i / 64, d = i % 64;
            q[((size_t)bh * T_PAD + t) * 64 + d] = 0;
            k[((size_t)bh * T_PAD + t) * 64 + d] = 0;
        }
        for (int i = tid; i < 4096; i += 256) {
            int d = i >> 6, s = 768 + (i & 63);
            vT[((size_t)bh * 64 + d) * T_PAD + s] = 0;
        }
    } else if (bid < 8620) {
        int i = bid - 4524;
        int z = i >> 10, rem = i & 1023;
        int bx = rem & 31, by = rem >> 5;
        const float* W = (z == 0) ? Wq : (z == 1) ? Wk : (z == 2) ? Wv : Wp;
        unsigned short* Wt = Wt_out + (size_t)z * 1048576;
        int tx = tid & 31, ty0 = tid >> 5;
#pragma unroll
        for (int j = 0; j < 4; ++j) {
            int ty = ty0 + j * 8;
            tile[ty][tx] = W[(size_t)(by * 32 + ty) * 1024 + bx * 32 + tx];
        }
        __syncthreads();
#pragma unroll
        for (int j = 0; j < 4; ++j) {
            int ty = ty0 + j * 8;
            Wt[(size_t)(bx * 32 + ty) * 1024 + by * 32 + tx] = f2bf(tile[tx][ty]);
        }
    } else {
        int i = bid - 8620;
        int m = i >> 10, rem = i & 1023, b = rem >> 8, r = rem & 255;
        const float* f  = (m == 0) ? f01 : (m == 1) ? f02 : f12;
        const float* bm = (m == 0) ? b01 : (m == 1) ? b02 : b12;
        int ii = tid >> 4, j = tid & 15;

        float k1[7]; float ks = 0.f;
#pragma unroll
        for (int d = 0; d < 7; ++d) { float hx = (float)d - 3.f; k1[d] = expf(-0.5f * hx * hx / 2.25f); ks += k1[d]; }
#pragma unroll
        for (int d = 0; d < 7; ++d) k1[d] /= ks;

        size_t idx = (size_t)b * 65536 + (size_t)r * 256 + tid;
        float bi = f[idx] * bm[(size_t)b * 65536 + (size_t)tid * 256 + r];
        img[ii][j] = bi;
        __syncthreads();
        float ha = 0.f;
#pragma unroll
        for (int d = 0; d < 7; ++d) { int p = j - 3 + d; p = p < 0 ? -p : (p > 15 ? 30 - p : p); ha += k1[d] * img[ii][p]; }
        tmp[ii][j] = ha;
        __syncthreads();
        float v = 0.f;
#pragma unroll
        for (int d = 0; d < 7; ++d) { int p = ii - 3 + d; p = p < 0 ? -p : (p > 15 ? 30 - p : p); v += k1[d] * tmp[p][j]; }
        bl[(size_t)m * 262144 + idx] = v;

        float mn = v, mx = v;
#pragma unroll
        for (int off = 32; off; off >>= 1) { mn = fminf(mn, __shfl_xor(mn, off)); mx = fmaxf(mx, __shfl_xor(mx, off)); }
        int wid = tid >> 6, lane = tid & 63;
        if (lane == 0) { smn[wid] = mn; smx[wid] = mx; }
        __syncthreads();
        if (tid == 0) {
            mn = fminf(fminf(smn[0], smn[1]), fminf(smn[2], smn[3]));
            mx = fmaxf(fmaxf(smx[0], smx[1]), fmaxf(smx[2], smx[3]));
            pmm[2 * i]     = mn;    // plain stores, no atomics
            pmm[2 * i + 1] = mx;
        }
    }
}

// ---------------- GEMM 128x128 tile + (MODE 0) fused finalize tail ----------------
// MODE 0: 1D grid 3696: [0,624) QKV GEMM (XCD-swizzled), [624,3696) finalize->cm
// MODE 2: 1D grid 208: proj GEMM f32 out (XCD-swizzled)
template<int MODE>
__global__ __launch_bounds__(256) void k_gemm(const unsigned short* __restrict__ A,
                                              const unsigned short* __restrict__ Bt,
                                              const float* __restrict__ b0, const float* __restrict__ b1,
                                              const float* __restrict__ b2,
                                              unsigned short* __restrict__ qo, unsigned short* __restrict__ ko,
                                              unsigned short* __restrict__ vo, float* __restrict__ fo, int M,
                                              const float* f01, const float* f02, const float* f12,
                                              const float* b01, const float* b02, const float* b12,
                                              const float* __restrict__ bl,
                                              const float* __restrict__ pmm,
                                              float* __restrict__ cm) {
    __shared__ unsigned short As[4096];
    __shared__ unsigned short Bs[4096];
    int bid = blockIdx.x, tid = threadIdx.x;

    if (MODE == 0 && bid >= 624) {
        // ---- finalize with inline min/max reduce (redundant per block, L2-hot) ----
        int i = bid - 624;
        int m = i >> 10, rem = i & 1023, b = rem >> 8, r = rem & 255;
        float mn = __builtin_inff(), mx = 0.f;
        for (int kk = tid; kk < 1024; kk += 256) {
            int e = m * 1024 + kk;
            mn = fminf(mn, pmm[2 * e]);
            mx = fmaxf(mx, pmm[2 * e + 1]);
        }
#pragma unroll
        for (int off = 32; off; off >>= 1) { mn = fminf(mn, __shfl_xor(mn, off)); mx = fmaxf(mx, __shfl_xor(mx, off)); }
        float* fs = reinterpret_cast<float*>(As);
        int wid = tid >> 6, lane = tid & 63;
        if (lane == 0) { fs[wid] = mn; fs[4 + wid] = mx; }
        __syncthreads();
        mn = fminf(fminf(fs[0], fs[1]), fminf(fs[2], fs[3]));
        mx = fmaxf(fmaxf(fs[4], fs[5]), fmaxf(fs[6], fs[7]));

        const float* f  = (m == 0) ? f01 : (m == 1) ? f02 : f12;
        const float* bm = (m == 0) ? b01 : (m == 1) ? b02 : b12;
        size_t idx = (size_t)b * 65536 + (size_t)r * 256 + tid;
        float w = (bl[(size_t)m * 262144 + idx] - mn) / (mx - mn);
        w = fminf(fmaxf(w, 0.f), 1.f);
        float val = w * f[idx] * bm[(size_t)b * 65536 + (size_t)tid * 256 + r];
        int row = (m == 0) ? r : r + 286;
        int col = (m == 2) ? tid + 286 : tid;
        cm[((size_t)b * 542 + row) * 544 + col] = val;
        return;
    }

    // ---- GEMM path, XCD-aware bijective swizzle ----
    int m0, n0;
    if (MODE == 0) {
        int swz = (bid & 7) * 78 + (bid >> 3);   // 624 = 8*78
        m0 = (swz % 26) * 128; n0 = (swz / 26) * 128;
    } else {
        int swz = (bid & 7) * 26 + (bid >> 3);   // 208 = 8*26
        m0 = (swz % 26) * 128; n0 = (swz / 26) * 128;
    }
    int wid = tid >> 6, lane = tid & 63;
    int g = lane >> 4, l15 = lane & 15;
    int wm = wid >> 1, wn = wid & 1;
    facc4 acc[4][4] = {};

    int ar0 = m0 + (tid >> 2); if (ar0 > M - 1) ar0 = M - 1;
    int ar1 = m0 + 64 + (tid >> 2); if (ar1 > M - 1) ar1 = M - 1;
    const unsigned short* Ap0 = A + (size_t)ar0 * 1024 + (tid & 3) * 8;
    const unsigned short* Ap1 = A + (size_t)ar1 * 1024 + (tid & 3) * 8;
    const unsigned short* Bp0 = Bt + (size_t)(n0 + (tid >> 2)) * 1024 + (tid & 3) * 8;
    const unsigned short* Bp1 = Bp0 + (size_t)64 * 1024;
    unsigned short* asw = As + (wid << 9);
    unsigned short* bsw = Bs + (wid << 9);

    for (int k0 = 0; k0 < 1024; k0 += 32) {
        if (k0) __syncthreads();
        gl16(Ap0 + k0, asw);
        gl16(Ap1 + k0, asw + 2048);
        gl16(Bp0 + k0, bsw);
        gl16(Bp1 + k0, bsw + 2048);
        __syncthreads();
        bfrag8 af[4], bf[4];
#pragma unroll
        for (int mi = 0; mi < 4; ++mi)
            af[mi] = *reinterpret_cast<const bfrag8*>(&As[(wm * 64 + mi * 16 + l15) * 32 + g * 8]);
#pragma unroll
        for (int ni = 0; ni < 4; ++ni)
            bf[ni] = *reinterpret_cast<const bfrag8*>(&Bs[(wn * 64 + ni * 16 + l15) * 32 + g * 8]);
#pragma unroll
        for (int mi = 0; mi < 4; ++mi)
#pragma unroll
            for (int ni = 0; ni < 4; ++ni)
                acc[mi][ni] = MFMA16(af[mi], bf[ni], acc[mi][ni]);
    }

    int which = n0 >> 10;
    const float* bb = (MODE == 2) ? b0 : (which == 0 ? b0 : (which == 1 ? b1 : b2));
#pragma unroll
    for (int mi = 0; mi < 4; ++mi)
#pragma unroll
        for (int ni = 0; ni < 4; ++ni)
#pragma unroll
            for (int r = 0; r < 4; ++r) {
                int row = m0 + wm * 64 + mi * 16 + g * 4 + r;
                if (row >= M) continue;
                int col = n0 + wn * 64 + ni * 16 + l15;
                float v = acc[mi][ni][r] + bb[col & 1023];
                if (MODE == 2) {
                    fo[(size_t)row * 1024 + col] = v;
                } else {
                    int b = row / T_SEQ, t = row - b * T_SEQ;
                    int cc = col & 1023;
                    int hh = cc >> 6, d = cc & 63;
                    size_t bh = (size_t)(b * NHEAD + hh);
                    if (which == 0) {
                        qo[(bh * T_PAD + t) * 64 + d] = f2bf(v);
                    } else if (which == 1) {
                        int du = (((d >> 3) ^ (t & 7)) << 3) | (d & 7);
                        ko[(bh * T_PAD + t) * 64 + du] = f2bf(v);
                    } else {
                        int sl = t & 63;
                        int su = (((sl >> 3) ^ (d & 7)) << 3) | (t & 7);
                        vo[(bh * 64 + d) * T_PAD + (t - sl) + su] = f2bf(v);
                    }
                }
            }
}

// ---------------- flash attention v4: swapped QK^T, defer-max, XCD swizzle --------
__global__ __launch_bounds__(256) void k_attn(const unsigned short* __restrict__ qb,
                                              const unsigned short* __restrict__ kb,
                                              const unsigned short* __restrict__ vT,
                                              const float* __restrict__ h,
                                              const float* __restrict__ cm,
                                              unsigned short* __restrict__ y) {
    int blk0 = blockIdx.x;
    int blk = (blk0 & 7) * 104 + (blk0 >> 3);   // 832 = 8*104, bijective XCD chunks
    int bh = blk / 13;
    int qt = 12 - (blk % 13);       // long blocks first within each bh
    int b = bh >> 4, hh = bh & 15;
    int tid = threadIdx.x, wid = tid >> 6, lane = tid & 63;
    int g = lane >> 4, l15 = lane & 15;
    int t0 = qt * 64 + wid * 16;
    int t = t0 + l15;               // this lane's t-column
    int tcl = t > 826 ? 826 : t;
    int ntiles = qt + 1;

    __shared__ unsigned short Ks[2][4096];
    __shared__ unsigned short Vs[2][4096];
    __shared__ unsigned short Ps[4][1024];
    unsigned short* pw = &Ps[wid][0];

    const unsigned short* Kbase = kb + (size_t)bh * T_PAD * 64;
    const unsigned short* Vbase = vT + (size_t)bh * 64 * T_PAD;
    const float* hrow = h + (size_t)bh * T_SEQ * T_SEQ + (size_t)tcl * T_SEQ;
    int rt = t - 285; rt = rt < 0 ? 0 : (rt > 541 ? 541 : rt);
    const float* cmrow = cm + ((size_t)b * 542 + rt) * 544;
    bool tm = (t >= 285);

    // Q fragments (B-operand; lane l15 = t-column)
    size_t qrow = ((size_t)bh * T_PAD + t) * 64 + g * 8;
    bfrag8 aq0 = *reinterpret_cast<const bfrag8*>(qb + qrow);
    bfrag8 aq1 = *reinterpret_cast<const bfrag8*>(qb + qrow + 32);

    auto stage = [&](int s0, int buf) {
        const unsigned short* kt = Kbase + (size_t)s0 * 64;
        unsigned short* kd = &Ks[buf][0] + (wid << 9);
        gl16(kt + tid * 8, kd);
        gl16(kt + 2048 + tid * 8, kd + 2048);
        const unsigned short* vt = Vbase + s0;
        unsigned short* vd = &Vs[buf][0] + (wid << 9);
        gl16(vt + (size_t)(tid >> 3) * T_PAD + (tid & 7) * 8, vd);
        gl16(vt + (size_t)((tid >> 3) + 32) * T_PAD + (tid & 7) * 8, vd + 2048);
    };

    auto loadh = [&](int s0t, float* hv, float* mv) {
#pragma unroll
        for (int nt = 0; nt < 4; ++nt) {
            int sb = s0t + nt * 16 + 4 * g;
            float h4[4];
            if (sb + 3 <= tcl) {
                __builtin_memcpy(h4, hrow + sb, 16);
            } else {
#pragma unroll
                for (int j = 0; j < 4; ++j) {
                    float hx = 0.f;
                    if (sb + j <= tcl) hx = hrow[sb + j];
                    h4[j] = hx;
                }
            }
            float m4[4];
            if (tm && sb <= 540) {
                __builtin_memcpy(m4, cmrow + sb, 16);
            } else {
#pragma unroll
                for (int j = 0; j < 4; ++j) m4[j] = 1.f;
            }
#pragma unroll
            for (int j = 0; j < 4; ++j) { hv[nt * 4 + j] = h4[j]; mv[nt * 4 + j] = m4[j]; }
        }
    };

    float m_r = NEG_INF, l_r = 0.f;
    facc4 acc[4] = {};
    float hv[16], mv[16];
    loadh(0, hv, mv);
    stage(0, 0);

    for (int it = 0; it < ntiles; ++it) {
        int cur = it & 1, s0 = it * 64;
        bool more = (it + 1 < ntiles);
        bool diag = !more;                 // last tile contains the diagonal
        __syncthreads();                   // stage(it) complete
        if (more) stage(s0 + 64, cur ^ 1);

        // ---- QK^T (swapped: A=K, B=Q) -> lane holds S[s=s0+nt*16+4g+r][t] ----
        facc4 sf[4] = {};
        __builtin_amdgcn_s_setprio(1);
#pragma unroll
        for (int nt = 0; nt < 4; ++nt) {
            int row = nt * 16 + l15;
            const unsigned short* kp = &Ks[cur][row * 64];
            bfrag8 k0 = *reinterpret_cast<const bfrag8*>(kp + ((g ^ (row & 7)) << 3));
            bfrag8 k1 = *reinterpret_cast<const bfrag8*>(kp + (((4 + g) ^ (row & 7)) << 3));
            sf[nt] = MFMA16(k0, aq0, sf[nt]);
            sf[nt] = MFMA16(k1, aq1, sf[nt]);
        }
        __builtin_amdgcn_s_setprio(0);

        // ---- score + in-register partial max ----
        float vmax = NEG_INF;
#pragma unroll
        for (int nt = 0; nt < 4; ++nt)
#pragma unroll
            for (int r = 0; r < 4; ++r) {
                float val = fmaf(sf[nt][r], 0.125f, hv[nt * 4 + r]) * mv[nt * 4 + r];
                if (diag) {
                    int s = s0 + nt * 16 + 4 * g + r;
                    val = (s <= tcl) ? val : NEG_INF;
                }
                sf[nt][r] = val;
                vmax = fmaxf(vmax, val);
            }

        if (more) loadh(s0 + 64, hv, mv);  // prefetch next tile's h/mask

        vmax = fmaxf(vmax, __shfl_xor(vmax, 16));
        vmax = fmaxf(vmax, __shfl_xor(vmax, 32));

        // ---- defer-max (T13): skip rescale when growth <= THR ----
        bool noresc = __all(vmax <= m_r + 6.0f);
        float mnew = fmaxf(m_r, vmax);
        float mexp = noresc ? m_r : mnew;

        float ps = 0.f;
#pragma unroll
        for (int nt = 0; nt < 4; ++nt)
#pragma unroll
            for (int r = 0; r < 4; ++r) {
                float p = __expf(sf[nt][r] - mexp);
                sf[nt][r] = p;
                ps += p;
            }
        ps += __shfl_xor(ps, 16);
        ps += __shfl_xor(ps, 32);

        // ---- pack P (bf16) -> LDS [t][s] swizzled ----
#pragma unroll
        for (int nt = 0; nt < 4; ++nt) {
            unsigned u0, u1;
            asm("v_cvt_pk_bf16_f32 %0, %1, %2" : "=v"(u0) : "v"(sf[nt][0]), "v"(sf[nt][1]));
            asm("v_cvt_pk_bf16_f32 %0, %1, %2" : "=v"(u1) : "v"(sf[nt][2]), "v"(sf[nt][3]));
            int el = (l15 * 64 + nt * 16 + 4 * g) ^ ((l15 & 7) << 3);
            uint2 uu; uu.x = u0; uu.y = u1;
            *reinterpret_cast<uint2*>(&pw[el]) = uu;
        }

        // ---- online-softmax state update ----
        if (!noresc) {
            float scale = __expf(m_r - mnew);
            l_r = l_r * scale + ps;
#pragma unroll
            for (int r = 0; r < 4; ++r) {
                float sc = __int_as_float(__builtin_amdgcn_ds_bpermute((4 * g + r) * 4, __float_as_int(scale)));
#pragma unroll
                for (int dt = 0; dt < 4; ++dt) acc[dt][r] *= sc;
            }
            m_r = mnew;
        } else {
            l_r += ps;
        }

        // ---- PV: A=P (LDS), B=V^T (LDS) ----
        __builtin_amdgcn_s_setprio(1);
#pragma unroll
        for (int c2 = 0; c2 < 2; ++c2) {
            int ela = (l15 * 64 + c2 * 32 + 8 * g) ^ ((l15 & 7) << 3);
            bfrag8 ap = *reinterpret_cast<const bfrag8*>(&pw[ela]);
#pragma unroll
            for (int dt = 0; dt < 4; ++dt) {
                int row = dt * 16 + l15;
                bfrag8 vf = *reinterpret_cast<const bfrag8*>(&Vs[cur][row * 64 + (((c2 * 4 + g) ^ (row & 7)) << 3)]);
                acc[dt] = MFMA16(ap, vf, acc[dt]);
            }
        }
        __builtin_amdgcn_s_setprio(0);
    }

    float linv = 1.0f / l_r;
#pragma unroll
    for (int r = 0; r < 4; ++r) {
        float li = __int_as_float(__builtin_amdgcn_ds_bpermute((4 * g + r) * 4, __float_as_int(linv)));
        int tt = t0 + 4 * g + r;
        if (tt < T_SEQ) {
#pragma unroll
            for (int dt = 0; dt < 4; ++dt)
                y[((size_t)(b * T_SEQ) + tt) * 1024 + hh * 64 + dt * 16 + l15] = f2bf(acc[dt][r] * li);
        }
    }
}

extern "C" void kernel_launch(void* const* d_in, const int* in_sizes, int n_in,
                              void* d_out, int out_size, void* d_ws, size_t ws_size,
                              hipStream_t stream) {
    const float* x   = (const float*)d_in[0];
    const float* h   = (const float*)d_in[1];
    const float* f01 = (const float*)d_in[2];
    const float* f02 = (const float*)d_in[3];
    const float* f12 = (const float*)d_in[4];
    const float* b01 = (const float*)d_in[5];
    const float* b02 = (const float*)d_in[6];
    const float* b12 = (const float*)d_in[7];
    const float* Wq  = (const float*)d_in[8];
    const float* bq  = (const float*)d_in[9];
    const float* Wk  = (const float*)d_in[10];
    const float* bk  = (const float*)d_in[11];
    const float* Wv  = (const float*)d_in[12];
    const float* bv  = (const float*)d_in[13];
    const float* Wp  = (const float*)d_in[14];
    const float* bp  = (const float*)d_in[15];

    char* ws = (char*)d_ws;
    float* pmm    = (float*)(ws + 256);               // 3072*2*4 = 24576 B
    float* bl     = (float*)(ws + 256 + 24576);       // 3 MB
    float* cmb    = (float*)(ws + 256 + 24576 + 3145728);  // 4.7 MB
    unsigned short* x_bf  = (unsigned short*)(ws + 256 + 24576 + 3145728 + 4717568);
    unsigned short* WtQKV = x_bf + (size_t)3308 * 1024;
    unsigned short* WtP   = WtQKV + (size_t)3072 * 1024;
    unsigned short* q_bf  = WtP + (size_t)1024 * 1024;
    unsigned short* k_bf  = q_bf + (size_t)64 * T_PAD * 64;
    unsigned short* vTb   = k_bf + (size_t)64 * T_PAD * 64;
    unsigned short* y_bf  = vTb  + (size_t)64 * T_PAD * 64;

    k_front<<<11692, 256, 0, stream>>>(x, x_bf, cmb, q_bf, k_bf, vTb,
                                       Wq, Wk, Wv, Wp, WtQKV,
                                       f01, f02, f12, b01, b02, b12, bl, pmm);
    // QKV GEMM (624 blocks) + finalize tail (3072 blocks)
    k_gemm<0><<<3696, 256, 0, stream>>>(x_bf, WtQKV, bq, bk, bv, q_bf, k_bf, vTb, nullptr, 3308,
                                        f01, f02, f12, b01, b02, b12, bl, pmm, cmb);
    k_attn<<<832, 256, 0, stream>>>(q_bf, k_bf, vTb, h, cmb, y_bf);
    k_gemm<2><<<208, 256, 0, stream>>>(y_bf, WtP, bp, nullptr, nullptr, nullptr, nullptr, nullptr,
                                       (float*)d_out, 3308,
                                       nullptr, nullptr, nullptr, nullptr, nullptr, nullptr,
                                       nullptr, nullptr, nullptr);
}